// Round 1
// baseline (568.402 us; speedup 1.0000x reference)
//
#include <hip/hip_runtime.h>
#include <hip/hip_bf16.h>
#include <math.h>

#define NPTS 4096
#define FIN 512
#define FOUT 64

typedef __attribute__((ext_vector_type(8))) short bf16x8;
typedef __attribute__((ext_vector_type(4))) float f32x4;

// ---------------- prep: bf16 copy of h, row norms, init m1 ----------------
__global__ __launch_bounds__(256) void k_prep(const float* __restrict__ h,
    __hip_bfloat16* __restrict__ xb, float* __restrict__ sq, int* __restrict__ m1) {
  int row = blockIdx.x, t = threadIdx.x;
  const float* hr = h + (size_t)row * FIN;
  float v0 = hr[t], v1 = hr[t + 256];
  xb[(size_t)row * FIN + t] = __float2bfloat16(v0);
  xb[(size_t)row * FIN + t + 256] = __float2bfloat16(v1);
  float s = v0 * v0 + v1 * v1;
  #pragma unroll
  for (int mm = 1; mm < 64; mm <<= 1) s += __shfl_xor(s, mm);
  __shared__ float wsv[4];
  int lane = t & 63, wid = t >> 6;
  if (lane == 0) wsv[wid] = s;
  __syncthreads();
  if (t == 0) {
    sq[row] = wsv[0] + wsv[1] + wsv[2] + wsv[3];
    m1[row] = 0x7F800000; // +inf bits
  }
}

// ---------------- Wh = h @ W ----------------
__global__ __launch_bounds__(256) void k_wh(const float* __restrict__ h,
    const float* __restrict__ W, float* __restrict__ Wh) {
  int j = threadIdx.x & 63;
  int i = blockIdx.x * 4 + (threadIdx.x >> 6);
  const float* hr = h + (size_t)i * FIN;
  float acc = 0.f;
  #pragma unroll 8
  for (int k = 0; k < FIN; ++k) acc = fmaf(hr[k], W[k * FOUT + j], acc);
  Wh[(size_t)i * FOUT + j] = acc;
}

// ---------------- Gram + per-row NN-min (bf16 MFMA, upper-tri blocks) ----------------
__global__ __launch_bounds__(256) void k_gram(const __hip_bfloat16* __restrict__ xb,
    const float* __restrict__ sq, int* __restrict__ m1) {
  int J = blockIdx.x, I = blockIdx.y;
  if (J < I) return;
  int tid = threadIdx.x, lane = tid & 63, wid = tid >> 6;
  int rowBase = I * 128 + (wid >> 1) * 64;
  int colBase = J * 128 + (wid & 1) * 64;
  int lrow = lane & 15, lk = (lane >> 4) * 8, rsub = (lane >> 4) * 4;

  f32x4 acc[4][4];
  #pragma unroll
  for (int a = 0; a < 4; ++a)
    #pragma unroll
    for (int b = 0; b < 4; ++b)
      acc[a][b] = (f32x4){0.f, 0.f, 0.f, 0.f};

  const __hip_bfloat16* aptr = xb + (size_t)(rowBase + lrow) * FIN + lk;
  const __hip_bfloat16* bptr = xb + (size_t)(colBase + lrow) * FIN + lk;
  for (int kk = 0; kk < FIN; kk += 32) {
    bf16x8 av[4], bw[4];
    #pragma unroll
    for (int f = 0; f < 4; ++f) {
      av[f] = *reinterpret_cast<const bf16x8*>(aptr + (size_t)f * 16 * FIN + kk);
      bw[f] = *reinterpret_cast<const bf16x8*>(bptr + (size_t)f * 16 * FIN + kk);
    }
    #pragma unroll
    for (int fi = 0; fi < 4; ++fi)
      #pragma unroll
      for (int fj = 0; fj < 4; ++fj)
        acc[fi][fj] = __builtin_amdgcn_mfma_f32_16x16x32_bf16(av[fi], bw[fj], acc[fi][fj], 0, 0, 0);
  }

  float sqr[16], sqc4[4];
  #pragma unroll
  for (int fi = 0; fi < 4; ++fi)
    #pragma unroll
    for (int rg = 0; rg < 4; ++rg)
      sqr[fi * 4 + rg] = sq[rowBase + fi * 16 + rsub + rg];
  #pragma unroll
  for (int fj = 0; fj < 4; ++fj) sqc4[fj] = sq[colBase + fj * 16 + lrow];

  float rmin[16], cmin[4];
  #pragma unroll
  for (int q = 0; q < 16; ++q) rmin[q] = INFINITY;
  #pragma unroll
  for (int q = 0; q < 4; ++q) cmin[q] = INFINITY;

  #pragma unroll
  for (int fi = 0; fi < 4; ++fi)
    #pragma unroll
    for (int fj = 0; fj < 4; ++fj)
      #pragma unroll
      for (int rg = 0; rg < 4; ++rg) {
        int r = rowBase + fi * 16 + rsub + rg;
        int c = colBase + fj * 16 + lrow;
        float d2 = sqr[fi * 4 + rg] + sqc4[fj] - 2.f * acc[fi][fj][rg];
        if (r == c) d2 = INFINITY;
        rmin[fi * 4 + rg] = fminf(rmin[fi * 4 + rg], d2);
        cmin[fj] = fminf(cmin[fj], d2);
      }

  // reduce row-mins over the 16 lanes sharing the same row set (lane bits 0..3)
  #pragma unroll
  for (int mm = 1; mm < 16; mm <<= 1) {
    #pragma unroll
    for (int q = 0; q < 16; ++q) rmin[q] = fminf(rmin[q], __shfl_xor(rmin[q], mm));
  }
  if ((lane & 15) == 0) {
    #pragma unroll
    for (int q = 0; q < 16; ++q) {
      int r = rowBase + (q >> 2) * 16 + rsub + (q & 3);
      atomicMin(&m1[r], __float_as_int(rmin[q]));
    }
  }
  if (I != J) {
    // symmetric contribution: col j's min over these rows -> row j
    #pragma unroll
    for (int mm = 16; mm < 64; mm <<= 1) {
      #pragma unroll
      for (int q = 0; q < 4; ++q) cmin[q] = fminf(cmin[q], __shfl_xor(cmin[q], mm));
    }
    if ((lane >> 4) == 0) {
      #pragma unroll
      for (int q = 0; q < 4; ++q)
        atomicMin(&m1[colBase + q * 16 + lane], __float_as_int(cmin[q]));
    }
  }
}

// ---------------- dc = mean sqrt(relu(min d2)) ----------------
__global__ __launch_bounds__(1024) void k_dc(const int* __restrict__ m1, float* __restrict__ dcp) {
  int t = threadIdx.x;
  float s = 0.f;
  for (int i = t; i < NPTS; i += 1024) s += sqrtf(fmaxf(__int_as_float(m1[i]), 0.f));
  #pragma unroll
  for (int mm = 1; mm < 64; mm <<= 1) s += __shfl_xor(s, mm);
  __shared__ float wsv[16];
  if ((t & 63) == 0) wsv[t >> 6] = s;
  __syncthreads();
  if (t == 0) {
    float tot = 0.f;
    for (int w = 0; w < 16; ++w) tot += wsv[w];
    dcp[0] = tot / (float)NPTS;
  }
}

// ---------------- kmeans ----------------
__global__ __launch_bounds__(512) void k_km_init(const float* __restrict__ h, float* __restrict__ centers) {
  centers[threadIdx.x] = h[threadIdx.x];
}

__global__ __launch_bounds__(256) void k_km_d0(const float* __restrict__ h,
    const float* __restrict__ centers, float* __restrict__ dkm,
    float* __restrict__ bestv, int* __restrict__ besti) {
  int t = threadIdx.x, lane = t & 63, wid = t >> 6;
  int base = blockIdx.x * 256 + wid * 64;
  float bv = -1.f; int bi = 0;
  float myd = 0.f;
  for (int r = 0; r < 64; ++r) {
    int row = base + r;
    const float* xr = h + (size_t)row * FIN;
    float d = 0.f;
    #pragma unroll
    for (int m = 0; m < 8; ++m) {
      float df = xr[lane + 64 * m] - centers[lane + 64 * m];
      d = fmaf(df, df, d);
    }
    #pragma unroll
    for (int mm = 1; mm < 64; mm <<= 1) d += __shfl_xor(d, mm);
    if (r == lane) myd = d;
    if (d > bv) { bv = d; bi = row; }
  }
  dkm[base + lane] = myd;
  __shared__ float wbv[4]; __shared__ int wbi[4];
  if (lane == 0) { wbv[wid] = bv; wbi[wid] = bi; }
  __syncthreads();
  if (t == 0) {
    float v = wbv[0]; int i0 = wbi[0];
    for (int w = 1; w < 4; ++w)
      if (wbv[w] > v || (wbv[w] == v && wbi[w] < i0)) { v = wbv[w]; i0 = wbi[w]; }
    bestv[blockIdx.x] = v; besti[blockIdx.x] = i0;
  }
}

__global__ __launch_bounds__(256) void k_km_d1(const float* __restrict__ h,
    const float* __restrict__ centers, float* __restrict__ dkm,
    float* __restrict__ bestv, int* __restrict__ besti) {
  int t = threadIdx.x, lane = t & 63, wid = t >> 6;
  int base = blockIdx.x * 256 + wid * 64;
  float bv = -1.f; int bi = 0;
  float myd = 0.f;
  for (int r = 0; r < 64; ++r) {
    int row = base + r;
    const float* xr = h + (size_t)row * FIN;
    float d = 0.f;
    #pragma unroll
    for (int m = 0; m < 8; ++m) {
      float df = xr[lane + 64 * m] - centers[FIN + lane + 64 * m];
      d = fmaf(df, df, d);
    }
    #pragma unroll
    for (int mm = 1; mm < 64; mm <<= 1) d += __shfl_xor(d, mm);
    d = fminf(d, dkm[row]);
    if (r == lane) myd = d;
    if (d > bv) { bv = d; bi = row; }
  }
  dkm[base + lane] = myd;
  __shared__ float wbv[4]; __shared__ int wbi[4];
  if (lane == 0) { wbv[wid] = bv; wbi[wid] = bi; }
  __syncthreads();
  if (t == 0) {
    float v = wbv[0]; int i0 = wbi[0];
    for (int w = 1; w < 4; ++w)
      if (wbv[w] > v || (wbv[w] == v && wbi[w] < i0)) { v = wbv[w]; i0 = wbi[w]; }
    bestv[blockIdx.x] = v; besti[blockIdx.x] = i0;
  }
}

__global__ __launch_bounds__(512) void k_km_pick(const float* __restrict__ h,
    const float* __restrict__ bestv, const int* __restrict__ besti,
    float* __restrict__ centers, int cidx) {
  __shared__ int sbi;
  if (threadIdx.x == 0) {
    float v = bestv[0]; int b = besti[0];
    for (int k = 1; k < 16; ++k)
      if (bestv[k] > v || (bestv[k] == v && besti[k] < b)) { v = bestv[k]; b = besti[k]; }
    sbi = b;
  }
  __syncthreads();
  centers[cidx * FIN + threadIdx.x] = h[(size_t)sbi * FIN + threadIdx.x];
}

__global__ __launch_bounds__(256) void k_km_assign(const float* __restrict__ h,
    const float* __restrict__ sq, const float* __restrict__ centers,
    float* __restrict__ psums, float* __restrict__ pcnts) {
  int t = threadIdx.x, lane = t & 63, wid = t >> 6;
  __shared__ float sqc_s[3];
  __shared__ float wsum[4][3][512];
  __shared__ float wcnt[4][3];
  if (wid < 3) {
    float s = 0.f;
    #pragma unroll
    for (int m = 0; m < 8; ++m) { float c = centers[wid * FIN + lane + 64 * m]; s = fmaf(c, c, s); }
    #pragma unroll
    for (int mm = 1; mm < 64; mm <<= 1) s += __shfl_xor(s, mm);
    if (lane == 0) sqc_s[wid] = s;
  }
  for (int idx = t; idx < 4 * 3 * 512; idx += 256) ((float*)wsum)[idx] = 0.f;
  if (t < 12) ((float*)wcnt)[t] = 0.f;
  __syncthreads();

  float ps0[8], ps1[8], ps2[8];
  #pragma unroll
  for (int m = 0; m < 8; ++m) { ps0[m] = 0.f; ps1[m] = 0.f; ps2[m] = 0.f; }
  int pc0 = 0, pc1 = 0, pc2 = 0;
  int rbase = blockIdx.x * 64 + wid * 16;
  for (int r = 0; r < 16; ++r) {
    int row = rbase + r;
    const float* xr = h + (size_t)row * FIN;
    float xv[8]; float d0 = 0.f, d1 = 0.f, d2 = 0.f;
    #pragma unroll
    for (int m = 0; m < 8; ++m) {
      xv[m] = xr[lane + 64 * m];
      d0 = fmaf(xv[m], centers[0 * FIN + lane + 64 * m], d0);
      d1 = fmaf(xv[m], centers[1 * FIN + lane + 64 * m], d1);
      d2 = fmaf(xv[m], centers[2 * FIN + lane + 64 * m], d2);
    }
    #pragma unroll
    for (int mm = 1; mm < 64; mm <<= 1) {
      d0 += __shfl_xor(d0, mm); d1 += __shfl_xor(d1, mm); d2 += __shfl_xor(d2, mm);
    }
    float sr = sq[row];
    float e0 = sr + sqc_s[0] - 2.f * d0;
    float e1 = sr + sqc_s[1] - 2.f * d1;
    float e2 = sr + sqc_s[2] - 2.f * d2;
    int bc = 0; float bd = e0;
    if (e1 < bd) { bd = e1; bc = 1; }
    if (e2 < bd) { bd = e2; bc = 2; }
    if (bc == 0) {
      #pragma unroll
      for (int m = 0; m < 8; ++m) ps0[m] += xv[m];
      pc0++;
    } else if (bc == 1) {
      #pragma unroll
      for (int m = 0; m < 8; ++m) ps1[m] += xv[m];
      pc1++;
    } else {
      #pragma unroll
      for (int m = 0; m < 8; ++m) ps2[m] += xv[m];
      pc2++;
    }
  }
  #pragma unroll
  for (int m = 0; m < 8; ++m) {
    wsum[wid][0][lane + 64 * m] = ps0[m];
    wsum[wid][1][lane + 64 * m] = ps1[m];
    wsum[wid][2][lane + 64 * m] = ps2[m];
  }
  if (lane == 0) {
    wcnt[wid][0] = (float)pc0; wcnt[wid][1] = (float)pc1; wcnt[wid][2] = (float)pc2;
  }
  __syncthreads();
  for (int idx = t; idx < 1536; idx += 256) {
    float s = 0.f;
    for (int w = 0; w < 4; ++w) s += ((float*)wsum)[w * 1536 + idx];
    psums[(size_t)blockIdx.x * 1536 + idx] = s;
  }
  if (t < 3) pcnts[blockIdx.x * 3 + t] = wcnt[0][t] + wcnt[1][t] + wcnt[2][t] + wcnt[3][t];
}

__global__ __launch_bounds__(256) void k_km_update(const float* __restrict__ psums,
    const float* __restrict__ pcnts, float* __restrict__ centers) {
  int gid = blockIdx.x * 256 + threadIdx.x; // < 1536
  int c = gid / 512;
  float cnt = 0.f, s = 0.f;
  for (int b = 0; b < 64; ++b) { cnt += pcnts[b * 3 + c]; s += psums[(size_t)b * 1536 + gid]; }
  centers[gid] = s / fmaxf(cnt, 1.f);
}

// ---------------- d1val[i,c] = dc * d1[i,1] / d1[i,c]^2 ----------------
__global__ __launch_bounds__(256) void k_d1val(const float* __restrict__ h,
    const float* __restrict__ sq, const float* __restrict__ centers,
    const float* __restrict__ dcp, float* __restrict__ d1v) {
  int t = threadIdx.x, lane = t & 63, wid = t >> 6;
  __shared__ float sqc_s[3];
  if (wid < 3) {
    float s = 0.f;
    #pragma unroll
    for (int m = 0; m < 8; ++m) { float c = centers[wid * FIN + lane + 64 * m]; s = fmaf(c, c, s); }
    #pragma unroll
    for (int mm = 1; mm < 64; mm <<= 1) s += __shfl_xor(s, mm);
    if (lane == 0) sqc_s[wid] = s;
  }
  __syncthreads();
  float dcv = dcp[0];
  int base = blockIdx.x * 256 + wid * 64;
  for (int r = 0; r < 64; ++r) {
    int row = base + r;
    const float* xr = h + (size_t)row * FIN;
    float d0 = 0.f, d1 = 0.f, d2 = 0.f;
    #pragma unroll
    for (int m = 0; m < 8; ++m) {
      float xv = xr[lane + 64 * m];
      d0 = fmaf(xv, centers[0 * FIN + lane + 64 * m], d0);
      d1 = fmaf(xv, centers[1 * FIN + lane + 64 * m], d1);
      d2 = fmaf(xv, centers[2 * FIN + lane + 64 * m], d2);
    }
    #pragma unroll
    for (int mm = 1; mm < 64; mm <<= 1) {
      d0 += __shfl_xor(d0, mm); d1 += __shfl_xor(d1, mm); d2 += __shfl_xor(d2, mm);
    }
    if (lane == 0) {
      float sr = sq[row];
      float q0 = sqrtf(fmaxf(sr + sqc_s[0] - 2.f * d0, 0.f));
      float q1 = sqrtf(fmaxf(sr + sqc_s[1] - 2.f * d1, 0.f));
      float q2 = sqrtf(fmaxf(sr + sqc_s[2] - 2.f * d2, 0.f));
      float nearest = q1;
      d1v[row * 3 + 0] = (q0 != 0.f) ? (dcv * nearest / (q0 * q0)) : 0.f;
      d1v[row * 3 + 1] = (q1 != 0.f) ? (dcv * nearest / (q1 * q1)) : 0.f;
      d1v[row * 3 + 2] = (q2 != 0.f) ? (dcv * nearest / (q2 * q2)) : 0.f;
    }
  }
}

// ---------------- bottom 3 output rows: one-hot at argmin colsum(t2) ----------------
__global__ __launch_bounds__(1024) void k_kstar(const float* __restrict__ t2,
    const float* __restrict__ Wh, float* __restrict__ out) {
  int t = threadIdx.x, lane = t & 63, wid = t >> 6;
  __shared__ float sbv[16]; __shared__ int sbk[16];
  __shared__ int kstar;
  float bv = INFINITY; int bk = 0x7FFFFFFF;
  for (int k = t; k < NPTS; k += 1024) {
    float v = t2[k] + t2[NPTS + k] + t2[2 * NPTS + k];
    if (v < bv || (v == bv && k < bk)) { bv = v; bk = k; }
  }
  #pragma unroll
  for (int mm = 1; mm < 64; mm <<= 1) {
    float ov = __shfl_xor(bv, mm); int ok = __shfl_xor(bk, mm);
    if (ov < bv || (ov == bv && ok < bk)) { bv = ov; bk = ok; }
  }
  if (lane == 0) { sbv[wid] = bv; sbk[wid] = bk; }
  __syncthreads();
  if (t == 0) {
    float v = sbv[0]; int b = sbk[0];
    for (int w = 1; w < 16; ++w)
      if (sbv[w] < v || (sbv[w] == v && sbk[w] < b)) { v = sbv[w]; b = sbk[w]; }
    kstar = b;
  }
  __syncthreads();
  if (t < 192) {
    int c = t >> 6, j = t & 63;
    float wv = Wh[(size_t)kstar * FOUT + j];
    out[(size_t)(NPTS + c) * FOUT + j] = wv > 0.f ? wv : expm1f(wv);
  }
}

// ---------------- fused softmax(d1val . t2) @ Wh + ELU ----------------
__global__ __launch_bounds__(512) void k_main(const float* __restrict__ t2,
    const float* __restrict__ Wh, const float* __restrict__ d1v,
    float* __restrict__ out) {
  int t = threadIdx.x, lane = t & 63, wid = t >> 6;
  int R0 = blockIdx.x * 16;
  __shared__ float dv[16][3];
  __shared__ float Ms[16];
  __shared__ float Lp[16][512];
  __shared__ float Sred[16];
  if (t < 48) ((float*)dv)[t] = d1v[R0 * 3 + t];
  __syncthreads();
  // pass 1: per-row max logit (include the 3 zero logits of the pad cols)
  {
    int r0 = 2 * wid, r1 = 2 * wid + 1;
    float a0 = dv[r0][0], a1 = dv[r0][1], a2 = dv[r0][2];
    float b0 = dv[r1][0], b1 = dv[r1][1], b2 = dv[r1][2];
    float m0 = -INFINITY, m1v = -INFINITY;
    for (int k = lane; k < NPTS; k += 64) {
      float c0 = t2[k], c1 = t2[NPTS + k], c2 = t2[2 * NPTS + k];
      float L0 = fmaf(a0, c0, fmaf(a1, c1, a2 * c2));
      float L1 = fmaf(b0, c0, fmaf(b1, c1, b2 * c2));
      m0 = fmaxf(m0, L0); m1v = fmaxf(m1v, L1);
    }
    #pragma unroll
    for (int mm = 1; mm < 64; mm <<= 1) {
      m0 = fmaxf(m0, __shfl_xor(m0, mm));
      m1v = fmaxf(m1v, __shfl_xor(m1v, mm));
    }
    if (lane == 0) { Ms[r0] = fmaxf(m0, 0.f); Ms[r1] = fmaxf(m1v, 0.f); }
  }
  __syncthreads();
  float Sp[16];
  #pragma unroll
  for (int r = 0; r < 16; ++r) Sp[r] = 0.f;
  float V0 = 0.f, V1 = 0.f;
  int rw0 = 2 * wid, rw1 = 2 * wid + 1;
  for (int cb = 0; cb < NPTS; cb += 512) {
    { // phase a: fill prob chunk
      int k = cb + t;
      float c0 = t2[k], c1 = t2[NPTS + k], c2 = t2[2 * NPTS + k];
      #pragma unroll
      for (int r = 0; r < 16; ++r) {
        float L = fmaf(dv[r][0], c0, fmaf(dv[r][1], c1, dv[r][2] * c2));
        float p = __expf(L - Ms[r]);
        Lp[r][t] = p;
        Sp[r] += p;
      }
    }
    __syncthreads();
    // phase b: weighted accumulation with Wh
    for (int kk = 0; kk < 512; ++kk) {
      float whv = Wh[(size_t)(cb + kk) * FOUT + lane];
      V0 = fmaf(Lp[rw0][kk], whv, V0);
      V1 = fmaf(Lp[rw1][kk], whv, V1);
    }
    __syncthreads();
  }
  // deterministic S reduction (reuse Lp)
  float* Lpf = (float*)Lp;
  #pragma unroll
  for (int r = 0; r < 16; ++r) Lpf[r * 512 + t] = Sp[r];
  __syncthreads();
  if (t < 16) {
    float s = 0.f;
    for (int q = 0; q < 512; ++q) s += Lpf[t * 512 + q];
    Sred[t] = s + 3.f * __expf(0.f - Ms[t]);
  }
  __syncthreads();
  {
    float o0 = V0 / Sred[rw0];
    float o1 = V1 / Sred[rw1];
    out[(size_t)(R0 + rw0) * FOUT + lane] = o0 > 0.f ? o0 : expm1f(o0);
    out[(size_t)(R0 + rw1) * FOUT + lane] = o1 > 0.f ? o1 : expm1f(o1);
  }
}

extern "C" void kernel_launch(void* const* d_in, const int* in_sizes, int n_in,
                              void* d_out, int out_size, void* d_ws, size_t ws_size,
                              hipStream_t stream) {
  const float* h  = (const float*)d_in[0];
  const float* W  = (const float*)d_in[2];
  const float* t2 = (const float*)d_in[5];
  float* out = (float*)d_out;

  char* ws = (char*)d_ws;
  __hip_bfloat16* xb = (__hip_bfloat16*)ws;
  float* F = (float*)(ws + (size_t)NPTS * FIN * 2);
  float* sq      = F;                    // 4096
  int*   m1      = (int*)(F + 4096);     // 4096
  float* dkm     = F + 8192;             // 4096
  float* d1v     = F + 12288;            // 12288
  float* Wh      = F + 24576;            // 262144
  float* centers = F + 286720;           // 1536
  float* bestv   = F + 288256;           // 16
  int*   besti   = (int*)(F + 288272);   // 16
  float* psums   = F + 288288;           // 98304
  float* pcnts   = F + 386592;           // 192
  float* dcp     = F + 386784;           // 1

  k_prep<<<NPTS, 256, 0, stream>>>(h, xb, sq, m1);
  k_wh<<<NPTS / 4, 256, 0, stream>>>(h, W, Wh);
  k_gram<<<dim3(32, 32), 256, 0, stream>>>(xb, sq, m1);
  k_dc<<<1, 1024, 0, stream>>>(m1, dcp);

  k_km_init<<<1, 512, 0, stream>>>(h, centers);
  k_km_d0<<<16, 256, 0, stream>>>(h, centers, dkm, bestv, besti);
  k_km_pick<<<1, 512, 0, stream>>>(h, bestv, besti, centers, 1);
  k_km_d1<<<16, 256, 0, stream>>>(h, centers, dkm, bestv, besti);
  k_km_pick<<<1, 512, 0, stream>>>(h, bestv, besti, centers, 2);
  for (int it = 0; it < 10; ++it) {
    k_km_assign<<<64, 256, 0, stream>>>(h, sq, centers, psums, pcnts);
    k_km_update<<<6, 256, 0, stream>>>(psums, pcnts, centers);
  }
  k_d1val<<<16, 256, 0, stream>>>(h, sq, centers, dcp, d1v);

  k_kstar<<<1, 1024, 0, stream>>>(t2, Wh, out);
  k_main<<<NPTS / 16, 512, 0, stream>>>(t2, Wh, d1v, out);
}

// Round 2
// 352.503 us; speedup vs baseline: 1.6125x; 1.6125x over previous
//
#include <hip/hip_runtime.h>
#include <hip/hip_bf16.h>
#include <math.h>

#define NPTS 4096
#define FIN 512
#define FOUT 64

typedef __attribute__((ext_vector_type(8))) short bf16x8;
typedef __attribute__((ext_vector_type(4))) float f32x4;

static __device__ __forceinline__ unsigned short bfbits(float x) {
  __hip_bfloat16 b = __float2bfloat16(x);
  return *reinterpret_cast<unsigned short*>(&b);
}

// ---------------- prep: bf16 copy of h, row norms, init m1 ----------------
__global__ __launch_bounds__(256) void k_prep(const float* __restrict__ h,
    __hip_bfloat16* __restrict__ xb, float* __restrict__ sq, int* __restrict__ m1) {
  int t = threadIdx.x, lane = t & 63, wid = t >> 6;
  int row = blockIdx.x * 4 + wid;
  const float4* hr = (const float4*)(h + (size_t)row * FIN);
  float4 a = hr[lane], b = hr[64 + lane];
  ushort4 pa = { bfbits(a.x), bfbits(a.y), bfbits(a.z), bfbits(a.w) };
  ushort4 pb = { bfbits(b.x), bfbits(b.y), bfbits(b.z), bfbits(b.w) };
  *(ushort4*)(xb + (size_t)row * FIN + 4 * lane) = pa;
  *(ushort4*)(xb + (size_t)row * FIN + 256 + 4 * lane) = pb;
  float s = a.x*a.x + a.y*a.y + a.z*a.z + a.w*a.w
          + b.x*b.x + b.y*b.y + b.z*b.z + b.w*b.w;
  #pragma unroll
  for (int mm = 1; mm < 64; mm <<= 1) s += __shfl_xor(s, mm);
  if (lane == 0) { sq[row] = s; m1[row] = 0x7F800000; }
}

// ---------------- Wh = h @ W ----------------
__global__ __launch_bounds__(256) void k_wh(const float* __restrict__ h,
    const float* __restrict__ W, float* __restrict__ Wh) {
  int j = threadIdx.x & 63;
  int i = blockIdx.x * 4 + (threadIdx.x >> 6);
  const float4* hr = (const float4*)(h + (size_t)i * FIN);
  float acc = 0.f;
  #pragma unroll 4
  for (int k4 = 0; k4 < 128; ++k4) {
    float4 hv = hr[k4];
    acc = fmaf(hv.x, W[(4*k4+0)*FOUT+j], acc);
    acc = fmaf(hv.y, W[(4*k4+1)*FOUT+j], acc);
    acc = fmaf(hv.z, W[(4*k4+2)*FOUT+j], acc);
    acc = fmaf(hv.w, W[(4*k4+3)*FOUT+j], acc);
  }
  Wh[(size_t)i * FOUT + j] = acc;
}

// ---------------- transpose Wh -> WhbT (bf16, [64][4096]) ----------------
__global__ __launch_bounds__(256) void k_tr(const float* __restrict__ Wh,
    __hip_bfloat16* __restrict__ WhbT) {
  __shared__ __hip_bfloat16 tT[64][264];  // padded: 264*2=528 keeps 16B row alignment
  int t = threadIdx.x;
  int kbase = blockIdx.x * 256;
  for (int rep = 0; rep < 64; ++rep) {
    int idx = t + rep * 256;
    int k = idx >> 6, n = idx & 63;
    tT[n][k] = __float2bfloat16(Wh[(size_t)(kbase + k) * FOUT + n]);
  }
  __syncthreads();
  int n = t >> 2, kq = t & 3;
  #pragma unroll
  for (int rep = 0; rep < 8; ++rep) {
    int kk = kq * 64 + rep * 8;
    bf16x8 v = *(const bf16x8*)&tT[n][kk];
    *(bf16x8*)(WhbT + (size_t)n * NPTS + kbase + kk) = v;
  }
}

// ---------------- Gram + per-row NN-min (bf16 MFMA, upper-tri blocks) ----------------
__global__ __launch_bounds__(256) void k_gram(const __hip_bfloat16* __restrict__ xb,
    const float* __restrict__ sq, int* __restrict__ m1) {
  int J = blockIdx.x, I = blockIdx.y;
  if (J < I) return;
  int tid = threadIdx.x, lane = tid & 63, wid = tid >> 6;
  int rowBase = I * 128 + (wid >> 1) * 64;
  int colBase = J * 128 + (wid & 1) * 64;
  int lrow = lane & 15, lk = (lane >> 4) * 8, rsub = (lane >> 4) * 4;

  f32x4 acc[4][4];
  #pragma unroll
  for (int a = 0; a < 4; ++a)
    #pragma unroll
    for (int b = 0; b < 4; ++b)
      acc[a][b] = (f32x4){0.f, 0.f, 0.f, 0.f};

  const __hip_bfloat16* aptr = xb + (size_t)(rowBase + lrow) * FIN + lk;
  const __hip_bfloat16* bptr = xb + (size_t)(colBase + lrow) * FIN + lk;
  for (int kk = 0; kk < FIN; kk += 32) {
    bf16x8 av[4], bw[4];
    #pragma unroll
    for (int f = 0; f < 4; ++f) {
      av[f] = *reinterpret_cast<const bf16x8*>(aptr + (size_t)f * 16 * FIN + kk);
      bw[f] = *reinterpret_cast<const bf16x8*>(bptr + (size_t)f * 16 * FIN + kk);
    }
    #pragma unroll
    for (int fi = 0; fi < 4; ++fi)
      #pragma unroll
      for (int fj = 0; fj < 4; ++fj)
        acc[fi][fj] = __builtin_amdgcn_mfma_f32_16x16x32_bf16(av[fi], bw[fj], acc[fi][fj], 0, 0, 0);
  }

  float sqr[16], sqc4[4];
  #pragma unroll
  for (int fi = 0; fi < 4; ++fi)
    #pragma unroll
    for (int rg = 0; rg < 4; ++rg)
      sqr[fi * 4 + rg] = sq[rowBase + fi * 16 + rsub + rg];
  #pragma unroll
  for (int fj = 0; fj < 4; ++fj) sqc4[fj] = sq[colBase + fj * 16 + lrow];

  float rmin[16], cmin[4];
  #pragma unroll
  for (int q = 0; q < 16; ++q) rmin[q] = INFINITY;
  #pragma unroll
  for (int q = 0; q < 4; ++q) cmin[q] = INFINITY;

  #pragma unroll
  for (int fi = 0; fi < 4; ++fi)
    #pragma unroll
    for (int fj = 0; fj < 4; ++fj)
      #pragma unroll
      for (int rg = 0; rg < 4; ++rg) {
        int r = rowBase + fi * 16 + rsub + rg;
        int c = colBase + fj * 16 + lrow;
        float d2 = sqr[fi * 4 + rg] + sqc4[fj] - 2.f * acc[fi][fj][rg];
        if (r == c) d2 = INFINITY;
        rmin[fi * 4 + rg] = fminf(rmin[fi * 4 + rg], d2);
        cmin[fj] = fminf(cmin[fj], d2);
      }

  #pragma unroll
  for (int mm = 1; mm < 16; mm <<= 1) {
    #pragma unroll
    for (int q = 0; q < 16; ++q) rmin[q] = fminf(rmin[q], __shfl_xor(rmin[q], mm));
  }
  if ((lane & 15) == 0) {
    #pragma unroll
    for (int q = 0; q < 16; ++q) {
      int r = rowBase + (q >> 2) * 16 + rsub + (q & 3);
      atomicMin(&m1[r], __float_as_int(rmin[q]));
    }
  }
  if (I != J) {
    #pragma unroll
    for (int mm = 16; mm < 64; mm <<= 1) {
      #pragma unroll
      for (int q = 0; q < 4; ++q) cmin[q] = fminf(cmin[q], __shfl_xor(cmin[q], mm));
    }
    if ((lane >> 4) == 0) {
      #pragma unroll
      for (int q = 0; q < 4; ++q)
        atomicMin(&m1[colBase + q * 16 + lane], __float_as_int(cmin[q]));
    }
  }
}

// ---------------- dc = mean sqrt(relu(min d2)); tm[c] = max|t2[c,:]| ----------------
__global__ __launch_bounds__(1024) void k_dc(const int* __restrict__ m1,
    const float* __restrict__ t2, float* __restrict__ dcp, float* __restrict__ tm) {
  int t = threadIdx.x;
  __shared__ float wsv[16];
  float s = 0.f;
  for (int i = t; i < NPTS; i += 1024) s += sqrtf(fmaxf(__int_as_float(m1[i]), 0.f));
  #pragma unroll
  for (int mm = 1; mm < 64; mm <<= 1) s += __shfl_xor(s, mm);
  if ((t & 63) == 0) wsv[t >> 6] = s;
  __syncthreads();
  if (t == 0) {
    float tot = 0.f;
    for (int w = 0; w < 16; ++w) tot += wsv[w];
    dcp[0] = tot / (float)NPTS;
  }
  for (int c = 0; c < 3; ++c) {
    __syncthreads();
    float m = 0.f;
    for (int k = t; k < NPTS; k += 1024) m = fmaxf(m, fabsf(t2[c * NPTS + k]));
    #pragma unroll
    for (int mm = 1; mm < 64; mm <<= 1) m = fmaxf(m, __shfl_xor(m, mm));
    if ((t & 63) == 0) wsv[t >> 6] = m;
    __syncthreads();
    if (t == 0) {
      float mm2 = 0.f;
      for (int w = 0; w < 16; ++w) mm2 = fmaxf(mm2, wsv[w]);
      tm[c] = mm2;
    }
  }
}

// ---------------- kmeans: assign (3 modes) ----------------
// MODE 0: dist to c0=h[0], write dkm, argmax partials -> bvOut/biOut
// MODE 1: reduce bvIn/biIn -> b1; min with dkm; argmax partials -> bvOut/biOut
// MODE 2: Lloyd assign + partial sums/counts
template<int MODE>
__global__ __launch_bounds__(256) void k_asgn(const float* __restrict__ h,
    const float* __restrict__ sq, const float* __restrict__ centers,
    float* __restrict__ dkm,
    const float* __restrict__ bvIn, const int* __restrict__ biIn,
    float* __restrict__ bvOut, int* __restrict__ biOut,
    int* __restrict__ b1s, float* __restrict__ psums, float* __restrict__ pcnts) {
  int t = threadIdx.x, lane = t & 63, wid = t >> 6;
  __shared__ float wsum[4][1536];
  __shared__ float wred[16];
  __shared__ int   ired[16];
  int row0 = blockIdx.x * 16 + wid * 4;

  float4 cA0, cB0, cA1, cB1, cA2, cB2;
  float sqc0 = 0.f, sqc1 = 0.f, sqc2 = 0.f;

  if (MODE == 0) {
    cA0 = ((const float4*)h)[lane]; cB0 = ((const float4*)h)[64 + lane];
  } else if (MODE == 1) {
    float v = bvIn[t]; int bi = biIn[t];
    #pragma unroll
    for (int mm = 1; mm < 64; mm <<= 1) {
      float ov = __shfl_xor(v, mm); int oi = __shfl_xor(bi, mm);
      if (ov > v || (ov == v && oi < bi)) { v = ov; bi = oi; }
    }
    if (lane == 0) { wred[wid] = v; ired[wid] = bi; }
    __syncthreads();
    if (t == 0) {
      float vv = wred[0]; int ii = ired[0];
      for (int w = 1; w < 4; ++w)
        if (wred[w] > vv || (wred[w] == vv && ired[w] < ii)) { vv = wred[w]; ii = ired[w]; }
      ired[0] = ii;
      if (blockIdx.x == 0) b1s[0] = ii;
    }
    __syncthreads();
    int b1 = ired[0];
    cA0 = ((const float4*)(h + (size_t)b1 * FIN))[lane];
    cB0 = ((const float4*)(h + (size_t)b1 * FIN))[64 + lane];
    __syncthreads();  // guard: ired reused below
  } else {
    cA0 = ((const float4*)(centers + 0 * FIN))[lane]; cB0 = ((const float4*)(centers + 0 * FIN))[64 + lane];
    cA1 = ((const float4*)(centers + 1 * FIN))[lane]; cB1 = ((const float4*)(centers + 1 * FIN))[64 + lane];
    cA2 = ((const float4*)(centers + 2 * FIN))[lane]; cB2 = ((const float4*)(centers + 2 * FIN))[64 + lane];
    float s0 = cA0.x*cA0.x + cA0.y*cA0.y + cA0.z*cA0.z + cA0.w*cA0.w
             + cB0.x*cB0.x + cB0.y*cB0.y + cB0.z*cB0.z + cB0.w*cB0.w;
    float s1 = cA1.x*cA1.x + cA1.y*cA1.y + cA1.z*cA1.z + cA1.w*cA1.w
             + cB1.x*cB1.x + cB1.y*cB1.y + cB1.z*cB1.z + cB1.w*cB1.w;
    float s2 = cA2.x*cA2.x + cA2.y*cA2.y + cA2.z*cA2.z + cA2.w*cA2.w
             + cB2.x*cB2.x + cB2.y*cB2.y + cB2.z*cB2.z + cB2.w*cB2.w;
    #pragma unroll
    for (int mm = 1; mm < 64; mm <<= 1) {
      s0 += __shfl_xor(s0, mm); s1 += __shfl_xor(s1, mm); s2 += __shfl_xor(s2, mm);
    }
    sqc0 = s0; sqc1 = s1; sqc2 = s2;
  }

  if (MODE <= 1) {
    float bv = -1.f; int bbi = 0;
    for (int r = 0; r < 4; ++r) {
      int row = row0 + r;
      const float4* xr = (const float4*)(h + (size_t)row * FIN);
      float4 xa = xr[lane], xb4 = xr[64 + lane];
      float d, dx;
      dx = xa.x - cA0.x; d = dx * dx;
      dx = xa.y - cA0.y; d = fmaf(dx, dx, d);
      dx = xa.z - cA0.z; d = fmaf(dx, dx, d);
      dx = xa.w - cA0.w; d = fmaf(dx, dx, d);
      dx = xb4.x - cB0.x; d = fmaf(dx, dx, d);
      dx = xb4.y - cB0.y; d = fmaf(dx, dx, d);
      dx = xb4.z - cB0.z; d = fmaf(dx, dx, d);
      dx = xb4.w - cB0.w; d = fmaf(dx, dx, d);
      #pragma unroll
      for (int mm = 1; mm < 64; mm <<= 1) d += __shfl_xor(d, mm);
      if (MODE == 1) d = fminf(d, dkm[row]);
      if (lane == 0) dkm[row] = d;
      if (d > bv) { bv = d; bbi = row; }
    }
    if (lane == 0) { wred[wid] = bv; ired[wid] = bbi; }
    __syncthreads();
    if (t == 0) {
      float vv = wred[0]; int ii = ired[0];
      for (int w = 1; w < 4; ++w)
        if (wred[w] > vv || (wred[w] == vv && ired[w] < ii)) { vv = wred[w]; ii = ired[w]; }
      bvOut[blockIdx.x] = vv; biOut[blockIdx.x] = ii;
    }
  } else {
    float ps[3][8];
    #pragma unroll
    for (int c = 0; c < 3; ++c)
      #pragma unroll
      for (int q = 0; q < 8; ++q) ps[c][q] = 0.f;
    float cnt0 = 0.f, cnt1 = 0.f, cnt2 = 0.f;
    for (int r = 0; r < 4; ++r) {
      int row = row0 + r;
      const float4* xr = (const float4*)(h + (size_t)row * FIN);
      float4 xa = xr[lane], xb4 = xr[64 + lane];
      float d0, d1, d2;
      d0 = xa.x*cA0.x; d1 = xa.x*cA1.x; d2 = xa.x*cA2.x;
      d0 = fmaf(xa.y, cA0.y, d0); d1 = fmaf(xa.y, cA1.y, d1); d2 = fmaf(xa.y, cA2.y, d2);
      d0 = fmaf(xa.z, cA0.z, d0); d1 = fmaf(xa.z, cA1.z, d1); d2 = fmaf(xa.z, cA2.z, d2);
      d0 = fmaf(xa.w, cA0.w, d0); d1 = fmaf(xa.w, cA1.w, d1); d2 = fmaf(xa.w, cA2.w, d2);
      d0 = fmaf(xb4.x, cB0.x, d0); d1 = fmaf(xb4.x, cB1.x, d1); d2 = fmaf(xb4.x, cB2.x, d2);
      d0 = fmaf(xb4.y, cB0.y, d0); d1 = fmaf(xb4.y, cB1.y, d1); d2 = fmaf(xb4.y, cB2.y, d2);
      d0 = fmaf(xb4.z, cB0.z, d0); d1 = fmaf(xb4.z, cB1.z, d1); d2 = fmaf(xb4.z, cB2.z, d2);
      d0 = fmaf(xb4.w, cB0.w, d0); d1 = fmaf(xb4.w, cB1.w, d1); d2 = fmaf(xb4.w, cB2.w, d2);
      #pragma unroll
      for (int mm = 1; mm < 64; mm <<= 1) {
        d0 += __shfl_xor(d0, mm); d1 += __shfl_xor(d1, mm); d2 += __shfl_xor(d2, mm);
      }
      float sr = sq[row];
      float e0 = sr + sqc0 - 2.f * d0;
      float e1 = sr + sqc1 - 2.f * d1;
      float e2 = sr + sqc2 - 2.f * d2;
      int bc = 0; float bd = e0;
      if (e1 < bd) { bd = e1; bc = 1; }
      if (e2 < bd) { bd = e2; bc = 2; }
      float f0 = (bc == 0) ? 1.f : 0.f, f1 = (bc == 1) ? 1.f : 0.f, f2 = (bc == 2) ? 1.f : 0.f;
      ps[0][0] = fmaf(f0, xa.x, ps[0][0]); ps[1][0] = fmaf(f1, xa.x, ps[1][0]); ps[2][0] = fmaf(f2, xa.x, ps[2][0]);
      ps[0][1] = fmaf(f0, xa.y, ps[0][1]); ps[1][1] = fmaf(f1, xa.y, ps[1][1]); ps[2][1] = fmaf(f2, xa.y, ps[2][1]);
      ps[0][2] = fmaf(f0, xa.z, ps[0][2]); ps[1][2] = fmaf(f1, xa.z, ps[1][2]); ps[2][2] = fmaf(f2, xa.z, ps[2][2]);
      ps[0][3] = fmaf(f0, xa.w, ps[0][3]); ps[1][3] = fmaf(f1, xa.w, ps[1][3]); ps[2][3] = fmaf(f2, xa.w, ps[2][3]);
      ps[0][4] = fmaf(f0, xb4.x, ps[0][4]); ps[1][4] = fmaf(f1, xb4.x, ps[1][4]); ps[2][4] = fmaf(f2, xb4.x, ps[2][4]);
      ps[0][5] = fmaf(f0, xb4.y, ps[0][5]); ps[1][5] = fmaf(f1, xb4.y, ps[1][5]); ps[2][5] = fmaf(f2, xb4.y, ps[2][5]);
      ps[0][6] = fmaf(f0, xb4.z, ps[0][6]); ps[1][6] = fmaf(f1, xb4.z, ps[1][6]); ps[2][6] = fmaf(f2, xb4.z, ps[2][6]);
      ps[0][7] = fmaf(f0, xb4.w, ps[0][7]); ps[1][7] = fmaf(f1, xb4.w, ps[1][7]); ps[2][7] = fmaf(f2, xb4.w, ps[2][7]);
      cnt0 += f0; cnt1 += f1; cnt2 += f2;
    }
    #pragma unroll
    for (int c = 0; c < 3; ++c) {
      *(float4*)&wsum[wid][c * 512 + 4 * lane]       = make_float4(ps[c][0], ps[c][1], ps[c][2], ps[c][3]);
      *(float4*)&wsum[wid][c * 512 + 256 + 4 * lane] = make_float4(ps[c][4], ps[c][5], ps[c][6], ps[c][7]);
    }
    if (lane == 0) { wred[wid * 3 + 0] = cnt0; wred[wid * 3 + 1] = cnt1; wred[wid * 3 + 2] = cnt2; }
    __syncthreads();
    for (int idx = t; idx < 1536; idx += 256)
      psums[(size_t)blockIdx.x * 1536 + idx] = (wsum[0][idx] + wsum[1][idx]) + (wsum[2][idx] + wsum[3][idx]);
    if (t < 3) pcnts[blockIdx.x * 3 + t] = (wred[0 * 3 + t] + wred[1 * 3 + t]) + (wred[2 * 3 + t] + wred[3 * 3 + t]);
  }
}

// ---------------- kmeans: center update ----------------
__global__ __launch_bounds__(256) void k_upd(const float* __restrict__ psums,
    const float* __restrict__ pcnts, float* __restrict__ centers) {
  int t = threadIdx.x;
  int cb = blockIdx.x >> 1;
  __shared__ float cp[8];
  __shared__ float cnts;
  if (t < 8) {
    float s = 0.f;
    #pragma unroll 8
    for (int q = 0; q < 32; ++q) s += pcnts[(t * 32 + q) * 3 + cb];
    cp[t] = s;
  }
  __syncthreads();
  if (t == 0) cnts = ((cp[0] + cp[1]) + (cp[2] + cp[3])) + ((cp[4] + cp[5]) + (cp[6] + cp[7]));
  __syncthreads();
  int gid = blockIdx.x * 256 + t;
  float a0 = 0, a1 = 0, a2 = 0, a3 = 0, a4 = 0, a5 = 0, a6 = 0, a7 = 0;
  for (int b8 = 0; b8 < 32; ++b8) {
    const float* p = psums + (size_t)(b8 * 8) * 1536 + gid;
    a0 += p[0];        a1 += p[1536];     a2 += p[2 * 1536]; a3 += p[3 * 1536];
    a4 += p[4 * 1536]; a5 += p[5 * 1536]; a6 += p[6 * 1536]; a7 += p[7 * 1536];
  }
  float s = ((a0 + a1) + (a2 + a3)) + ((a4 + a5) + (a6 + a7));
  centers[gid] = s / fmaxf(cnts, 1.f);
}

// ---------------- kmeans: init centers (c0, c1=h[b1], c2=h[b2]) ----------------
__global__ __launch_bounds__(256) void k_initc(const float* __restrict__ h,
    const float* __restrict__ bvIn, const int* __restrict__ biIn,
    const int* __restrict__ b1s, float* __restrict__ centers) {
  int t = threadIdx.x, lane = t & 63, wid = t >> 6;
  __shared__ float wred[4]; __shared__ int ired[4]; __shared__ int sb2;
  float v = bvIn[t]; int bi = biIn[t];
  #pragma unroll
  for (int mm = 1; mm < 64; mm <<= 1) {
    float ov = __shfl_xor(v, mm); int oi = __shfl_xor(bi, mm);
    if (ov > v || (ov == v && oi < bi)) { v = ov; bi = oi; }
  }
  if (lane == 0) { wred[wid] = v; ired[wid] = bi; }
  __syncthreads();
  if (t == 0) {
    float vv = wred[0]; int ii = ired[0];
    for (int w = 1; w < 4; ++w)
      if (wred[w] > vv || (wred[w] == vv && ired[w] < ii)) { vv = wred[w]; ii = ired[w]; }
    sb2 = ii;
  }
  __syncthreads();
  int b1 = b1s[0], b2 = sb2;
  for (int idx = t; idx < 1536; idx += 256) {
    int c = idx >> 9, d = idx & 511;
    int row = (c == 0) ? 0 : ((c == 1) ? b1 : b2);
    centers[idx] = h[(size_t)row * FIN + d];
  }
}

// ---------------- d1val[i,c] = dc * d1[i,1] / d1[i,c]^2 ----------------
__global__ __launch_bounds__(256) void k_d1val(const float* __restrict__ h,
    const float* __restrict__ sq, const float* __restrict__ centers,
    const float* __restrict__ dcp, float* __restrict__ d1v) {
  int t = threadIdx.x, lane = t & 63, wid = t >> 6;
  float4 cA0 = ((const float4*)(centers + 0 * FIN))[lane], cB0 = ((const float4*)(centers + 0 * FIN))[64 + lane];
  float4 cA1 = ((const float4*)(centers + 1 * FIN))[lane], cB1 = ((const float4*)(centers + 1 * FIN))[64 + lane];
  float4 cA2 = ((const float4*)(centers + 2 * FIN))[lane], cB2 = ((const float4*)(centers + 2 * FIN))[64 + lane];
  float s0 = cA0.x*cA0.x + cA0.y*cA0.y + cA0.z*cA0.z + cA0.w*cA0.w
           + cB0.x*cB0.x + cB0.y*cB0.y + cB0.z*cB0.z + cB0.w*cB0.w;
  float s1 = cA1.x*cA1.x + cA1.y*cA1.y + cA1.z*cA1.z + cA1.w*cA1.w
           + cB1.x*cB1.x + cB1.y*cB1.y + cB1.z*cB1.z + cB1.w*cB1.w;
  float s2 = cA2.x*cA2.x + cA2.y*cA2.y + cA2.z*cA2.z + cA2.w*cA2.w
           + cB2.x*cB2.x + cB2.y*cB2.y + cB2.z*cB2.z + cB2.w*cB2.w;
  #pragma unroll
  for (int mm = 1; mm < 64; mm <<= 1) {
    s0 += __shfl_xor(s0, mm); s1 += __shfl_xor(s1, mm); s2 += __shfl_xor(s2, mm);
  }
  float dcv = dcp[0];
  int row0 = blockIdx.x * 16 + wid * 4;
  for (int r = 0; r < 4; ++r) {
    int row = row0 + r;
    const float4* xr = (const float4*)(h + (size_t)row * FIN);
    float4 xa = xr[lane], xb4 = xr[64 + lane];
    float d0, d1, d2;
    d0 = xa.x*cA0.x; d1 = xa.x*cA1.x; d2 = xa.x*cA2.x;
    d0 = fmaf(xa.y, cA0.y, d0); d1 = fmaf(xa.y, cA1.y, d1); d2 = fmaf(xa.y, cA2.y, d2);
    d0 = fmaf(xa.z, cA0.z, d0); d1 = fmaf(xa.z, cA1.z, d1); d2 = fmaf(xa.z, cA2.z, d2);
    d0 = fmaf(xa.w, cA0.w, d0); d1 = fmaf(xa.w, cA1.w, d1); d2 = fmaf(xa.w, cA2.w, d2);
    d0 = fmaf(xb4.x, cB0.x, d0); d1 = fmaf(xb4.x, cB1.x, d1); d2 = fmaf(xb4.x, cB2.x, d2);
    d0 = fmaf(xb4.y, cB0.y, d0); d1 = fmaf(xb4.y, cB1.y, d1); d2 = fmaf(xb4.y, cB2.y, d2);
    d0 = fmaf(xb4.z, cB0.z, d0); d1 = fmaf(xb4.z, cB1.z, d1); d2 = fmaf(xb4.z, cB2.z, d2);
    d0 = fmaf(xb4.w, cB0.w, d0); d1 = fmaf(xb4.w, cB1.w, d1); d2 = fmaf(xb4.w, cB2.w, d2);
    #pragma unroll
    for (int mm = 1; mm < 64; mm <<= 1) {
      d0 += __shfl_xor(d0, mm); d1 += __shfl_xor(d1, mm); d2 += __shfl_xor(d2, mm);
    }
    if (lane == 0) {
      float sr = sq[row];
      float q0 = sqrtf(fmaxf(sr + s0 - 2.f * d0, 0.f));
      float q1 = sqrtf(fmaxf(sr + s1 - 2.f * d1, 0.f));
      float q2 = sqrtf(fmaxf(sr + s2 - 2.f * d2, 0.f));
      float nr = q1;
      d1v[row * 3 + 0] = (q0 != 0.f) ? (dcv * nr / (q0 * q0)) : 0.f;
      d1v[row * 3 + 1] = (q1 != 0.f) ? (dcv * nr / (q1 * q1)) : 0.f;
      d1v[row * 3 + 2] = (q2 != 0.f) ? (dcv * nr / (q2 * q2)) : 0.f;
    }
  }
}

// ---------------- bottom 3 output rows: one-hot at argmin colsum(t2) ----------------
__global__ __launch_bounds__(1024) void k_kstar(const float* __restrict__ t2,
    const float* __restrict__ Wh, float* __restrict__ out) {
  int t = threadIdx.x, lane = t & 63, wid = t >> 6;
  __shared__ float sbv[16]; __shared__ int sbk[16];
  __shared__ int kstar;
  float bv = INFINITY; int bk = 0x7FFFFFFF;
  for (int k = t; k < NPTS; k += 1024) {
    float v = t2[k] + t2[NPTS + k] + t2[2 * NPTS + k];
    if (v < bv || (v == bv && k < bk)) { bv = v; bk = k; }
  }
  #pragma unroll
  for (int mm = 1; mm < 64; mm <<= 1) {
    float ov = __shfl_xor(bv, mm); int ok = __shfl_xor(bk, mm);
    if (ov < bv || (ov == bv && ok < bk)) { bv = ov; bk = ok; }
  }
  if (lane == 0) { sbv[wid] = bv; sbk[wid] = bk; }
  __syncthreads();
  if (t == 0) {
    float v = sbv[0]; int b = sbk[0];
    for (int w = 1; w < 16; ++w)
      if (sbv[w] < v || (sbv[w] == v && sbk[w] < b)) { v = sbv[w]; b = sbk[w]; }
    kstar = b;
  }
  __syncthreads();
  if (t < 192) {
    int c = t >> 6, j = t & 63;
    float wv = Wh[(size_t)kstar * FOUT + j];
    out[(size_t)(NPTS + c) * FOUT + j] = wv > 0.f ? wv : expm1f(wv);
  }
}

// ---------------- fused MFMA softmax-numerator @ Wh, K-split x4 ----------------
__global__ __launch_bounds__(256) void k_mainA(const float* __restrict__ t2,
    const __hip_bfloat16* __restrict__ WhbT, const float* __restrict__ d1v,
    const float* __restrict__ tm, float* __restrict__ Vpart, float* __restrict__ Spart) {
  int t = threadIdx.x, lane = t & 63, wid = t >> 6;
  int rb = blockIdx.x & 63, ks = blockIdx.x >> 6;
  int R0 = rb * 64, K0 = ks * 1024;
  __shared__ float t2s[3 * 1024];
  for (int idx = t; idx < 3072; idx += 256) {
    int c = idx >> 10, kl = idx & 1023;
    t2s[idx] = t2[c * NPTS + K0 + kl];
  }
  __syncthreads();
  int r = lane & 15, hi = lane >> 4;
  int row_g = R0 + wid * 16 + r;
  float a0 = d1v[row_g * 3 + 0], a1 = d1v[row_g * 3 + 1], a2 = d1v[row_g * 3 + 2];
  float M = fmaf(fabsf(a2), tm[2], fmaf(fabsf(a1), tm[1], fabsf(a0) * tm[0]));
  f32x4 acc[4];
  #pragma unroll
  for (int fn = 0; fn < 4; ++fn) acc[fn] = (f32x4){0.f, 0.f, 0.f, 0.f};
  float Sp = 0.f;
  const __hip_bfloat16* bwB[4];
  #pragma unroll
  for (int fn = 0; fn < 4; ++fn) bwB[fn] = WhbT + (size_t)(fn * 16 + r) * NPTS + K0 + hi * 8;

  for (int kst = 0; kst < 32; ++kst) {
    int kb = kst * 32 + hi * 8;
    f32x4 c0a = *(const f32x4*)&t2s[kb],           c0b = *(const f32x4*)&t2s[kb + 4];
    f32x4 c1a = *(const f32x4*)&t2s[1024 + kb],    c1b = *(const f32x4*)&t2s[1024 + kb + 4];
    f32x4 c2a = *(const f32x4*)&t2s[2048 + kb],    c2b = *(const f32x4*)&t2s[2048 + kb + 4];
    float pv[8];
    #pragma unroll
    for (int j = 0; j < 4; ++j) {
      float L  = fmaf(a0, c0a[j], fmaf(a1, c1a[j], fmaf(a2, c2a[j], -M)));
      pv[j] = __expf(L);
      float L2 = fmaf(a0, c0b[j], fmaf(a1, c1b[j], fmaf(a2, c2b[j], -M)));
      pv[4 + j] = __expf(L2);
    }
    Sp += ((pv[0] + pv[1]) + (pv[2] + pv[3])) + ((pv[4] + pv[5]) + (pv[6] + pv[7]));
    union { bf16x8 v; __hip_bfloat162 h2[4]; } pa;
    #pragma unroll
    for (int jj = 0; jj < 4; ++jj) {
      float2 f2; f2.x = pv[2 * jj]; f2.y = pv[2 * jj + 1];
      pa.h2[jj] = __float22bfloat162_rn(f2);
    }
    #pragma unroll
    for (int fn = 0; fn < 4; ++fn) {
      bf16x8 bw = *(const bf16x8*)(bwB[fn] + kst * 32);
      acc[fn] = __builtin_amdgcn_mfma_f32_16x16x32_bf16(pa.v, bw, acc[fn], 0, 0, 0);
    }
  }
  Sp += __shfl_xor(Sp, 16);
  Sp += __shfl_xor(Sp, 32);
  if (hi == 0) Spart[row_g * 4 + ks] = Sp;
  #pragma unroll
  for (int fn = 0; fn < 4; ++fn)
    #pragma unroll
    for (int q = 0; q < 4; ++q)
      Vpart[(size_t)ks * (NPTS * FOUT) + (size_t)(R0 + wid * 16 + hi * 4 + q) * FOUT + fn * 16 + r] = acc[fn][q];
}

// ---------------- combine partials: divide, ELU ----------------
__global__ __launch_bounds__(256) void k_comb(const float* __restrict__ Vpart,
    const float* __restrict__ Spart, const float* __restrict__ d1v,
    const float* __restrict__ tm, float* __restrict__ out) {
  int gid = blockIdx.x * 256 + threadIdx.x;
  int row = gid >> 6;
  float V = (Vpart[gid] + Vpart[NPTS * FOUT + gid])
          + (Vpart[2 * NPTS * FOUT + gid] + Vpart[3 * NPTS * FOUT + gid]);
  float s = (Spart[row * 4 + 0] + Spart[row * 4 + 1]) + (Spart[row * 4 + 2] + Spart[row * 4 + 3]);
  float a0 = d1v[row * 3 + 0], a1 = d1v[row * 3 + 1], a2 = d1v[row * 3 + 2];
  float M = fmaf(fabsf(a2), tm[2], fmaf(fabsf(a1), tm[1], fabsf(a0) * tm[0]));
  s += 3.f * __expf(-M);
  float o = V / s;
  out[gid] = o > 0.f ? o : expm1f(o);
}

extern "C" void kernel_launch(void* const* d_in, const int* in_sizes, int n_in,
                              void* d_out, int out_size, void* d_ws, size_t ws_size,
                              hipStream_t stream) {
  const float* h  = (const float*)d_in[0];
  const float* W  = (const float*)d_in[2];
  const float* t2 = (const float*)d_in[5];
  float* out = (float*)d_out;

  char* ws = (char*)d_ws;
  __hip_bfloat16* xb = (__hip_bfloat16*)ws;
  float* F = (float*)(ws + (size_t)NPTS * FIN * 2);
  float* sq      = F + 0;                  // 4096
  int*   m1      = (int*)(F + 4096);       // 4096
  float* dkm     = F + 8192;               // 4096
  float* d1v     = F + 16384;              // 12288
  float* Wh      = F + 32768;              // 262144
  float* centers = F + 294912;             // 1536
  float* bestv0  = F + 296448;             // 256
  int*   besti0  = (int*)(F + 296704);     // 256
  float* bestv1  = F + 296960;             // 256
  int*   besti1  = (int*)(F + 297216);     // 256
  int*   b1s     = (int*)(F + 297472);     // 4
  float* pcnts   = F + 297476;             // 768
  float* dcp     = F + 298244;             // 1
  float* tmv     = F + 298248;             // 3
  float* psums   = F + 298496;             // 393216
  float* Spart   = F + 691712;             // 16384
  float* Vpart   = F + 708096;             // 1048576
  __hip_bfloat16* WhbT = (__hip_bfloat16*)(F + 1756672); // 262144 bf16

  k_prep<<<NPTS / 4, 256, 0, stream>>>(h, xb, sq, m1);
  k_wh<<<NPTS / 4, 256, 0, stream>>>(h, W, Wh);
  k_tr<<<16, 256, 0, stream>>>(Wh, WhbT);
  k_gram<<<dim3(32, 32), 256, 0, stream>>>(xb, sq, m1);
  k_dc<<<1, 1024, 0, stream>>>(m1, t2, dcp, tmv);
  k_kstar<<<1, 1024, 0, stream>>>(t2, Wh, out);

  k_asgn<0><<<256, 256, 0, stream>>>(h, sq, centers, dkm, nullptr, nullptr,
                                     bestv0, besti0, b1s, psums, pcnts);
  k_asgn<1><<<256, 256, 0, stream>>>(h, sq, centers, dkm, bestv0, besti0,
                                     bestv1, besti1, b1s, psums, pcnts);
  k_initc<<<1, 256, 0, stream>>>(h, bestv1, besti1, b1s, centers);
  for (int it = 0; it < 10; ++it) {
    k_asgn<2><<<256, 256, 0, stream>>>(h, sq, centers, dkm, nullptr, nullptr,
                                       bestv0, besti0, b1s, psums, pcnts);
    k_upd<<<6, 256, 0, stream>>>(psums, pcnts, centers);
  }
  k_d1val<<<256, 256, 0, stream>>>(h, sq, centers, dcp, d1v);

  k_mainA<<<256, 256, 0, stream>>>(t2, WhbT, d1v, tmv, Vpart, Spart);
  k_comb<<<1024, 256, 0, stream>>>(Vpart, Spart, d1v, tmv, out);
}

// Round 3
// 293.690 us; speedup vs baseline: 1.9354x; 1.2003x over previous
//
#include <hip/hip_runtime.h>
#include <hip/hip_bf16.h>
#include <math.h>

#define NPTS 4096
#define FIN 512
#define FOUT 64

typedef __attribute__((ext_vector_type(8))) short bf16x8;
typedef __attribute__((ext_vector_type(4))) float f32x4;

static __device__ __forceinline__ unsigned short bfbits(float x) {
  __hip_bfloat16 b = __float2bfloat16(x);
  return *reinterpret_cast<unsigned short*>(&b);
}

// ---------------- prep: bf16 copy of h, row norms, init m1, Wh = h@W ----------------
__global__ __launch_bounds__(256) void k_prep(const float* __restrict__ h,
    const float* __restrict__ W, __hip_bfloat16* __restrict__ xb,
    float* __restrict__ sq, int* __restrict__ m1, float* __restrict__ Wh) {
  __shared__ float hs[4][512];
  int t = threadIdx.x, lane = t & 63, wid = t >> 6;
  int row = blockIdx.x * 4 + wid;
  const float4* hr = (const float4*)(h + (size_t)row * FIN);
  float4 a = hr[lane], b = hr[64 + lane];
  ushort4 pa = { bfbits(a.x), bfbits(a.y), bfbits(a.z), bfbits(a.w) };
  ushort4 pb = { bfbits(b.x), bfbits(b.y), bfbits(b.z), bfbits(b.w) };
  *(ushort4*)(xb + (size_t)row * FIN + 4 * lane) = pa;
  *(ushort4*)(xb + (size_t)row * FIN + 256 + 4 * lane) = pb;
  float s = a.x*a.x + a.y*a.y + a.z*a.z + a.w*a.w
          + b.x*b.x + b.y*b.y + b.z*b.z + b.w*b.w;
  #pragma unroll
  for (int mm = 1; mm < 64; mm <<= 1) s += __shfl_xor(s, mm);
  if (lane == 0) { sq[row] = s; m1[row] = 0x7F800000; }
  *(float4*)&hs[wid][4 * lane] = a;
  *(float4*)&hs[wid][256 + 4 * lane] = b;
  __syncthreads();
  // Wh: col = lane, 4 independent partial accumulators
  float a0 = 0.f, a1 = 0.f, a2 = 0.f, a3 = 0.f;
  #pragma unroll 2
  for (int k = 0; k < 512; k += 4) {
    a0 = fmaf(hs[wid][k + 0], W[(k + 0) * FOUT + lane], a0);
    a1 = fmaf(hs[wid][k + 1], W[(k + 1) * FOUT + lane], a1);
    a2 = fmaf(hs[wid][k + 2], W[(k + 2) * FOUT + lane], a2);
    a3 = fmaf(hs[wid][k + 3], W[(k + 3) * FOUT + lane], a3);
  }
  Wh[(size_t)row * FOUT + lane] = (a0 + a1) + (a2 + a3);
}

// ---------------- transpose Wh -> WhbT (bf16, [64][4096]) ----------------
__global__ __launch_bounds__(256) void k_tr(const float* __restrict__ Wh,
    __hip_bfloat16* __restrict__ WhbT) {
  __shared__ __hip_bfloat16 tT[64][264];
  int t = threadIdx.x;
  int kbase = blockIdx.x * 256;
  for (int rep = 0; rep < 64; ++rep) {
    int idx = t + rep * 256;
    int k = idx >> 6, n = idx & 63;
    tT[n][k] = __float2bfloat16(Wh[(size_t)(kbase + k) * FOUT + n]);
  }
  __syncthreads();
  int n = t >> 2, kq = t & 3;
  #pragma unroll
  for (int rep = 0; rep < 8; ++rep) {
    int kk = kq * 64 + rep * 8;
    bf16x8 v = *(const bf16x8*)&tT[n][kk];
    *(bf16x8*)(WhbT + (size_t)n * NPTS + kbase + kk) = v;
  }
}

// ---------------- Gram + per-row NN-min: LDS-staged MFMA, triangular grid ----------------
// 528 blocks = upper-tri (I<=J) of 32x32 128-tiles. BK=64, global_load_lds staging,
// XOR-swizzle (byte ^= (row&7)<<4) applied on global SOURCE + on ds_read (rule #21).
__global__ __launch_bounds__(256) void k_gram2(const __hip_bfloat16* __restrict__ xb,
    const float* __restrict__ sq, int* __restrict__ m1) {
  int b = blockIdx.x, I = 0;
  while (b >= 32 - I) { b -= 32 - I; ++I; }
  int J = I + b;
  int tid = threadIdx.x, lane = tid & 63, wid = tid >> 6;

  __shared__ __align__(16) __hip_bfloat16 As[128 * 64];
  __shared__ __align__(16) __hip_bfloat16 Bs[128 * 64];

  int R0 = I * 128, C0 = J * 128;
  int rowBase = (wid >> 1) * 64;   // within-tile
  int colBase = (wid & 1) * 64;
  int lrow = lane & 15, hi = lane >> 4, rsub = hi * 4;

  f32x4 acc[4][4];
  #pragma unroll
  for (int p = 0; p < 4; ++p)
    #pragma unroll
    for (int q = 0; q < 4; ++q)
      acc[p][q] = (f32x4){0.f, 0.f, 0.f, 0.f};

  // staging: wave w covers tile rows 32w..32w+31 (4 chunks of 8 rows x 128B)
  int srow = lane >> 3;                         // 0..7
  int scol = ((lane & 7) ^ srow) * 8;           // inverse-swizzled source col (elems)
  const __hip_bfloat16* gA = xb + (size_t)(R0 + wid * 32 + srow) * FIN + scol;
  const __hip_bfloat16* gB = xb + (size_t)(C0 + wid * 32 + srow) * FIN + scol;
  char* lA = (char*)As + wid * 4096;
  char* lB = (char*)Bs + wid * 4096;
  int rdswz = (lrow & 7) << 4;

  for (int kt = 0; kt < 8; ++kt) {
    int K0 = kt * 64;
    #pragma unroll
    for (int j = 0; j < 4; ++j) {
      __builtin_amdgcn_global_load_lds(
          (const __attribute__((address_space(1))) unsigned int*)(gA + (size_t)(8 * j) * FIN + K0),
          (__attribute__((address_space(3))) unsigned int*)(lA + j * 1024), 16, 0, 0);
      __builtin_amdgcn_global_load_lds(
          (const __attribute__((address_space(1))) unsigned int*)(gB + (size_t)(8 * j) * FIN + K0),
          (__attribute__((address_space(3))) unsigned int*)(lB + j * 1024), 16, 0, 0);
    }
    __syncthreads();
    #pragma unroll
    for (int s = 0; s < 2; ++s) {
      int k0b = s * 64;  // byte offset of k0 within row
      bf16x8 av[4], bw[4];
      #pragma unroll
      for (int f = 0; f < 4; ++f) {
        int arow = rowBase + f * 16 + lrow;
        av[f] = *(const bf16x8*)((const char*)As + arow * 128 + ((k0b + hi * 16) ^ rdswz));
        int brow = colBase + f * 16 + lrow;
        bw[f] = *(const bf16x8*)((const char*)Bs + brow * 128 + ((k0b + hi * 16) ^ rdswz));
      }
      #pragma unroll
      for (int fi = 0; fi < 4; ++fi)
        #pragma unroll
        for (int fj = 0; fj < 4; ++fj)
          acc[fi][fj] = __builtin_amdgcn_mfma_f32_16x16x32_bf16(av[fi], bw[fj], acc[fi][fj], 0, 0, 0);
    }
    __syncthreads();
  }

  int rowBaseG = R0 + rowBase, colBaseG = C0 + colBase;
  float sqr[16], sqc4[4];
  #pragma unroll
  for (int fi = 0; fi < 4; ++fi)
    #pragma unroll
    for (int rg = 0; rg < 4; ++rg)
      sqr[fi * 4 + rg] = sq[rowBaseG + fi * 16 + rsub + rg];
  #pragma unroll
  for (int fj = 0; fj < 4; ++fj) sqc4[fj] = sq[colBaseG + fj * 16 + lrow];

  float rmin[16], cmin[4];
  #pragma unroll
  for (int q = 0; q < 16; ++q) rmin[q] = INFINITY;
  #pragma unroll
  for (int q = 0; q < 4; ++q) cmin[q] = INFINITY;

  #pragma unroll
  for (int fi = 0; fi < 4; ++fi)
    #pragma unroll
    for (int fj = 0; fj < 4; ++fj)
      #pragma unroll
      for (int rg = 0; rg < 4; ++rg) {
        int r = rowBaseG + fi * 16 + rsub + rg;
        int c = colBaseG + fj * 16 + lrow;
        float d2 = sqr[fi * 4 + rg] + sqc4[fj] - 2.f * acc[fi][fj][rg];
        if (r == c) d2 = INFINITY;
        rmin[fi * 4 + rg] = fminf(rmin[fi * 4 + rg], d2);
        cmin[fj] = fminf(cmin[fj], d2);
      }

  #pragma unroll
  for (int mm = 1; mm < 16; mm <<= 1) {
    #pragma unroll
    for (int q = 0; q < 16; ++q) rmin[q] = fminf(rmin[q], __shfl_xor(rmin[q], mm));
  }
  if ((lane & 15) == 0) {
    #pragma unroll
    for (int q = 0; q < 16; ++q) {
      int r = rowBaseG + (q >> 2) * 16 + rsub + (q & 3);
      atomicMin(&m1[r], __float_as_int(rmin[q]));
    }
  }
  if (I != J) {
    #pragma unroll
    for (int mm = 16; mm < 64; mm <<= 1) {
      #pragma unroll
      for (int q = 0; q < 4; ++q) cmin[q] = fminf(cmin[q], __shfl_xor(cmin[q], mm));
    }
    if ((lane >> 4) == 0) {
      #pragma unroll
      for (int q = 0; q < 4; ++q)
        atomicMin(&m1[colBaseG + q * 16 + lane], __float_as_int(cmin[q]));
    }
  }
}

// ---------------- dc + tm + kstar (fused single-block) ----------------
__global__ __launch_bounds__(1024) void k_dckstar(const int* __restrict__ m1,
    const float* __restrict__ t2, const float* __restrict__ Wh,
    float* __restrict__ dcp, float* __restrict__ tm, float* __restrict__ out) {
  int t = threadIdx.x, lane = t & 63, wid = t >> 6;
  __shared__ float wsv[16];
  __shared__ int wsk[16];
  // dc
  float s = 0.f;
  for (int i = t; i < NPTS; i += 1024) s += sqrtf(fmaxf(__int_as_float(m1[i]), 0.f));
  #pragma unroll
  for (int mm = 1; mm < 64; mm <<= 1) s += __shfl_xor(s, mm);
  if (lane == 0) wsv[wid] = s;
  __syncthreads();
  if (t == 0) {
    float tot = 0.f;
    for (int w = 0; w < 16; ++w) tot += wsv[w];
    dcp[0] = tot / (float)NPTS;
  }
  // tm[c]
  for (int c = 0; c < 3; ++c) {
    __syncthreads();
    float m = 0.f;
    for (int k = t; k < NPTS; k += 1024) m = fmaxf(m, fabsf(t2[c * NPTS + k]));
    #pragma unroll
    for (int mm = 1; mm < 64; mm <<= 1) m = fmaxf(m, __shfl_xor(m, mm));
    if (lane == 0) wsv[wid] = m;
    __syncthreads();
    if (t == 0) {
      float mm2 = 0.f;
      for (int w = 0; w < 16; ++w) mm2 = fmaxf(mm2, wsv[w]);
      tm[c] = mm2;
    }
  }
  // kstar -> bottom 3 output rows
  __syncthreads();
  __shared__ int kstar;
  float bv = INFINITY; int bk = 0x7FFFFFFF;
  for (int k = t; k < NPTS; k += 1024) {
    float v = t2[k] + t2[NPTS + k] + t2[2 * NPTS + k];
    if (v < bv || (v == bv && k < bk)) { bv = v; bk = k; }
  }
  #pragma unroll
  for (int mm = 1; mm < 64; mm <<= 1) {
    float ov = __shfl_xor(bv, mm); int ok = __shfl_xor(bk, mm);
    if (ov < bv || (ov == bv && ok < bk)) { bv = ov; bk = ok; }
  }
  if (lane == 0) { wsv[wid] = bv; wsk[wid] = bk; }
  __syncthreads();
  if (t == 0) {
    float v = wsv[0]; int kk = wsk[0];
    for (int w = 1; w < 16; ++w)
      if (wsv[w] < v || (wsv[w] == v && wsk[w] < kk)) { v = wsv[w]; kk = wsk[w]; }
    kstar = kk;
  }
  __syncthreads();
  if (t < 192) {
    int c = t >> 6, j = t & 63;
    float wv = Wh[(size_t)kstar * FOUT + j];
    out[(size_t)(NPTS + c) * FOUT + j] = wv > 0.f ? wv : expm1f(wv);
  }
}

// ---------------- kmeans: assign (3 modes), 512 threads / 8 waves / 2 rows per wave ----------------
template<int MODE>
__global__ __launch_bounds__(512) void k_asgn(const float* __restrict__ h,
    const float* __restrict__ sq, const float* __restrict__ centers,
    float* __restrict__ dkm,
    const float* __restrict__ bvIn, const int* __restrict__ biIn,
    float* __restrict__ bvOut, int* __restrict__ biOut,
    int* __restrict__ b1s, float* __restrict__ psums, float* __restrict__ pcnts) {
  int t = threadIdx.x, lane = t & 63, wid = t >> 6;
  __shared__ float wsum[8][1536];
  __shared__ float wred[24];
  __shared__ int   ired[8];
  int row0 = blockIdx.x * 16 + wid * 2;

  float4 cA0, cB0, cA1, cB1, cA2, cB2;
  float sqc0 = 0.f, sqc1 = 0.f, sqc2 = 0.f;

  if (MODE == 0) {
    cA0 = ((const float4*)h)[lane]; cB0 = ((const float4*)h)[64 + lane];
  } else if (MODE == 1) {
    float v = (t < 256) ? bvIn[t] : -1e30f;
    int bi = (t < 256) ? biIn[t] : 0x7FFFFFFF;
    #pragma unroll
    for (int mm = 1; mm < 64; mm <<= 1) {
      float ov = __shfl_xor(v, mm); int oi = __shfl_xor(bi, mm);
      if (ov > v || (ov == v && oi < bi)) { v = ov; bi = oi; }
    }
    if (lane == 0) { wred[wid] = v; ired[wid] = bi; }
    __syncthreads();
    if (t == 0) {
      float vv = wred[0]; int ii = ired[0];
      for (int w = 1; w < 8; ++w)
        if (wred[w] > vv || (wred[w] == vv && ired[w] < ii)) { vv = wred[w]; ii = ired[w]; }
      ired[0] = ii;
      if (blockIdx.x == 0) b1s[0] = ii;
    }
    __syncthreads();
    int b1 = ired[0];
    cA0 = ((const float4*)(h + (size_t)b1 * FIN))[lane];
    cB0 = ((const float4*)(h + (size_t)b1 * FIN))[64 + lane];
    __syncthreads();
  } else {
    cA0 = ((const float4*)(centers + 0 * FIN))[lane]; cB0 = ((const float4*)(centers + 0 * FIN))[64 + lane];
    cA1 = ((const float4*)(centers + 1 * FIN))[lane]; cB1 = ((const float4*)(centers + 1 * FIN))[64 + lane];
    cA2 = ((const float4*)(centers + 2 * FIN))[lane]; cB2 = ((const float4*)(centers + 2 * FIN))[64 + lane];
    float s0 = cA0.x*cA0.x + cA0.y*cA0.y + cA0.z*cA0.z + cA0.w*cA0.w
             + cB0.x*cB0.x + cB0.y*cB0.y + cB0.z*cB0.z + cB0.w*cB0.w;
    float s1 = cA1.x*cA1.x + cA1.y*cA1.y + cA1.z*cA1.z + cA1.w*cA1.w
             + cB1.x*cB1.x + cB1.y*cB1.y + cB1.z*cB1.z + cB1.w*cB1.w;
    float s2 = cA2.x*cA2.x + cA2.y*cA2.y + cA2.z*cA2.z + cA2.w*cA2.w
             + cB2.x*cB2.x + cB2.y*cB2.y + cB2.z*cB2.z + cB2.w*cB2.w;
    #pragma unroll
    for (int mm = 1; mm < 64; mm <<= 1) {
      s0 += __shfl_xor(s0, mm); s1 += __shfl_xor(s1, mm); s2 += __shfl_xor(s2, mm);
    }
    sqc0 = s0; sqc1 = s1; sqc2 = s2;
  }

  if (MODE <= 1) {
    float bv = -1.f; int bbi = 0;
    for (int r = 0; r < 2; ++r) {
      int row = row0 + r;
      const float4* xr = (const float4*)(h + (size_t)row * FIN);
      float4 xa = xr[lane], xb4 = xr[64 + lane];
      float d, dx;
      dx = xa.x - cA0.x; d = dx * dx;
      dx = xa.y - cA0.y; d = fmaf(dx, dx, d);
      dx = xa.z - cA0.z; d = fmaf(dx, dx, d);
      dx = xa.w - cA0.w; d = fmaf(dx, dx, d);
      dx = xb4.x - cB0.x; d = fmaf(dx, dx, d);
      dx = xb4.y - cB0.y; d = fmaf(dx, dx, d);
      dx = xb4.z - cB0.z; d = fmaf(dx, dx, d);
      dx = xb4.w - cB0.w; d = fmaf(dx, dx, d);
      #pragma unroll
      for (int mm = 1; mm < 64; mm <<= 1) d += __shfl_xor(d, mm);
      if (MODE == 1) d = fminf(d, dkm[row]);
      if (lane == 0) dkm[row] = d;
      if (d > bv) { bv = d; bbi = row; }
    }
    if (lane == 0) { wred[wid] = bv; ired[wid] = bbi; }
    __syncthreads();
    if (t == 0) {
      float vv = wred[0]; int ii = ired[0];
      for (int w = 1; w < 8; ++w)
        if (wred[w] > vv || (wred[w] == vv && ired[w] < ii)) { vv = wred[w]; ii = ired[w]; }
      bvOut[blockIdx.x] = vv; biOut[blockIdx.x] = ii;
    }
  } else {
    float ps[3][8];
    #pragma unroll
    for (int c = 0; c < 3; ++c)
      #pragma unroll
      for (int q = 0; q < 8; ++q) ps[c][q] = 0.f;
    float cnt0 = 0.f, cnt1 = 0.f, cnt2 = 0.f;
    for (int r = 0; r < 2; ++r) {
      int row = row0 + r;
      const float4* xr = (const float4*)(h + (size_t)row * FIN);
      float4 xa = xr[lane], xb4 = xr[64 + lane];
      float d0, d1, d2;
      d0 = xa.x*cA0.x; d1 = xa.x*cA1.x; d2 = xa.x*cA2.x;
      d0 = fmaf(xa.y, cA0.y, d0); d1 = fmaf(xa.y, cA1.y, d1); d2 = fmaf(xa.y, cA2.y, d2);
      d0 = fmaf(xa.z, cA0.z, d0); d1 = fmaf(xa.z, cA1.z, d1); d2 = fmaf(xa.z, cA2.z, d2);
      d0 = fmaf(xa.w, cA0.w, d0); d1 = fmaf(xa.w, cA1.w, d1); d2 = fmaf(xa.w, cA2.w, d2);
      d0 = fmaf(xb4.x, cB0.x, d0); d1 = fmaf(xb4.x, cB1.x, d1); d2 = fmaf(xb4.x, cB2.x, d2);
      d0 = fmaf(xb4.y, cB0.y, d0); d1 = fmaf(xb4.y, cB1.y, d1); d2 = fmaf(xb4.y, cB2.y, d2);
      d0 = fmaf(xb4.z, cB0.z, d0); d1 = fmaf(xb4.z, cB1.z, d1); d2 = fmaf(xb4.z, cB2.z, d2);
      d0 = fmaf(xb4.w, cB0.w, d0); d1 = fmaf(xb4.w, cB1.w, d1); d2 = fmaf(xb4.w, cB2.w, d2);
      #pragma unroll
      for (int mm = 1; mm < 64; mm <<= 1) {
        d0 += __shfl_xor(d0, mm); d1 += __shfl_xor(d1, mm); d2 += __shfl_xor(d2, mm);
      }
      float sr = sq[row];
      float e0 = sr + sqc0 - 2.f * d0;
      float e1 = sr + sqc1 - 2.f * d1;
      float e2 = sr + sqc2 - 2.f * d2;
      int bc = 0; float bd = e0;
      if (e1 < bd) { bd = e1; bc = 1; }
      if (e2 < bd) { bd = e2; bc = 2; }
      float f0 = (bc == 0) ? 1.f : 0.f, f1 = (bc == 1) ? 1.f : 0.f, f2 = (bc == 2) ? 1.f : 0.f;
      ps[0][0] = fmaf(f0, xa.x, ps[0][0]); ps[1][0] = fmaf(f1, xa.x, ps[1][0]); ps[2][0] = fmaf(f2, xa.x, ps[2][0]);
      ps[0][1] = fmaf(f0, xa.y, ps[0][1]); ps[1][1] = fmaf(f1, xa.y, ps[1][1]); ps[2][1] = fmaf(f2, xa.y, ps[2][1]);
      ps[0][2] = fmaf(f0, xa.z, ps[0][2]); ps[1][2] = fmaf(f1, xa.z, ps[1][2]); ps[2][2] = fmaf(f2, xa.z, ps[2][2]);
      ps[0][3] = fmaf(f0, xa.w, ps[0][3]); ps[1][3] = fmaf(f1, xa.w, ps[1][3]); ps[2][3] = fmaf(f2, xa.w, ps[2][3]);
      ps[0][4] = fmaf(f0, xb4.x, ps[0][4]); ps[1][4] = fmaf(f1, xb4.x, ps[1][4]); ps[2][4] = fmaf(f2, xb4.x, ps[2][4]);
      ps[0][5] = fmaf(f0, xb4.y, ps[0][5]); ps[1][5] = fmaf(f1, xb4.y, ps[1][5]); ps[2][5] = fmaf(f2, xb4.y, ps[2][5]);
      ps[0][6] = fmaf(f0, xb4.z, ps[0][6]); ps[1][6] = fmaf(f1, xb4.z, ps[1][6]); ps[2][6] = fmaf(f2, xb4.z, ps[2][6]);
      ps[0][7] = fmaf(f0, xb4.w, ps[0][7]); ps[1][7] = fmaf(f1, xb4.w, ps[1][7]); ps[2][7] = fmaf(f2, xb4.w, ps[2][7]);
      cnt0 += f0; cnt1 += f1; cnt2 += f2;
    }
    #pragma unroll
    for (int c = 0; c < 3; ++c) {
      *(float4*)&wsum[wid][c * 512 + 4 * lane]       = make_float4(ps[c][0], ps[c][1], ps[c][2], ps[c][3]);
      *(float4*)&wsum[wid][c * 512 + 256 + 4 * lane] = make_float4(ps[c][4], ps[c][5], ps[c][6], ps[c][7]);
    }
    if (lane == 0) { wred[wid * 3 + 0] = cnt0; wred[wid * 3 + 1] = cnt1; wred[wid * 3 + 2] = cnt2; }
    __syncthreads();
    for (int idx = t; idx < 1536; idx += 512) {
      float ssum = ((wsum[0][idx] + wsum[1][idx]) + (wsum[2][idx] + wsum[3][idx]))
                 + ((wsum[4][idx] + wsum[5][idx]) + (wsum[6][idx] + wsum[7][idx]));
      psums[(size_t)blockIdx.x * 1536 + idx] = ssum;
    }
    if (t < 3) {
      float c = 0.f;
      for (int w = 0; w < 8; ++w) c += wred[w * 3 + t];
      pcnts[blockIdx.x * 3 + t] = c;
    }
  }
}

// ---------------- kmeans: center update ----------------
__global__ __launch_bounds__(256) void k_upd(const float* __restrict__ psums,
    const float* __restrict__ pcnts, float* __restrict__ centers) {
  int t = threadIdx.x;
  int cb = blockIdx.x >> 1;
  __shared__ float cp[8];
  __shared__ float cnts;
  if (t < 8) {
    float s = 0.f;
    #pragma unroll 8
    for (int q = 0; q < 32; ++q) s += pcnts[(t * 32 + q) * 3 + cb];
    cp[t] = s;
  }
  __syncthreads();
  if (t == 0) cnts = ((cp[0] + cp[1]) + (cp[2] + cp[3])) + ((cp[4] + cp[5]) + (cp[6] + cp[7]));
  __syncthreads();
  int gid = blockIdx.x * 256 + t;
  float a0 = 0, a1 = 0, a2 = 0, a3 = 0, a4 = 0, a5 = 0, a6 = 0, a7 = 0;
  for (int b8 = 0; b8 < 32; ++b8) {
    const float* p = psums + (size_t)(b8 * 8) * 1536 + gid;
    a0 += p[0];        a1 += p[1536];     a2 += p[2 * 1536]; a3 += p[3 * 1536];
    a4 += p[4 * 1536]; a5 += p[5 * 1536]; a6 += p[6 * 1536]; a7 += p[7 * 1536];
  }
  float s = ((a0 + a1) + (a2 + a3)) + ((a4 + a5) + (a6 + a7));
  centers[gid] = s / fmaxf(cnts, 1.f);
}

// ---------------- kmeans: init centers ----------------
__global__ __launch_bounds__(256) void k_initc(const float* __restrict__ h,
    const float* __restrict__ bvIn, const int* __restrict__ biIn,
    const int* __restrict__ b1s, float* __restrict__ centers) {
  int t = threadIdx.x, lane = t & 63, wid = t >> 6;
  __shared__ float wred[4]; __shared__ int ired[4]; __shared__ int sb2;
  float v = bvIn[t]; int bi = biIn[t];
  #pragma unroll
  for (int mm = 1; mm < 64; mm <<= 1) {
    float ov = __shfl_xor(v, mm); int oi = __shfl_xor(bi, mm);
    if (ov > v || (ov == v && oi < bi)) { v = ov; bi = oi; }
  }
  if (lane == 0) { wred[wid] = v; ired[wid] = bi; }
  __syncthreads();
  if (t == 0) {
    float vv = wred[0]; int ii = ired[0];
    for (int w = 1; w < 4; ++w)
      if (wred[w] > vv || (wred[w] == vv && ired[w] < ii)) { vv = wred[w]; ii = ired[w]; }
    sb2 = ii;
  }
  __syncthreads();
  int b1 = b1s[0], b2 = sb2;
  for (int idx = t; idx < 1536; idx += 256) {
    int c = idx >> 9, d = idx & 511;
    int row = (c == 0) ? 0 : ((c == 1) ? b1 : b2);
    centers[idx] = h[(size_t)row * FIN + d];
  }
}

// ---------------- d1val ----------------
__global__ __launch_bounds__(512) void k_d1val(const float* __restrict__ h,
    const float* __restrict__ sq, const float* __restrict__ centers,
    const float* __restrict__ dcp, float* __restrict__ d1v) {
  int t = threadIdx.x, lane = t & 63, wid = t >> 6;
  float4 cA0 = ((const float4*)(centers + 0 * FIN))[lane], cB0 = ((const float4*)(centers + 0 * FIN))[64 + lane];
  float4 cA1 = ((const float4*)(centers + 1 * FIN))[lane], cB1 = ((const float4*)(centers + 1 * FIN))[64 + lane];
  float4 cA2 = ((const float4*)(centers + 2 * FIN))[lane], cB2 = ((const float4*)(centers + 2 * FIN))[64 + lane];
  float s0 = cA0.x*cA0.x + cA0.y*cA0.y + cA0.z*cA0.z + cA0.w*cA0.w
           + cB0.x*cB0.x + cB0.y*cB0.y + cB0.z*cB0.z + cB0.w*cB0.w;
  float s1 = cA1.x*cA1.x + cA1.y*cA1.y + cA1.z*cA1.z + cA1.w*cA1.w
           + cB1.x*cB1.x + cB1.y*cB1.y + cB1.z*cB1.z + cB1.w*cB1.w;
  float s2 = cA2.x*cA2.x + cA2.y*cA2.y + cA2.z*cA2.z + cA2.w*cA2.w
           + cB2.x*cB2.x + cB2.y*cB2.y + cB2.z*cB2.z + cB2.w*cB2.w;
  #pragma unroll
  for (int mm = 1; mm < 64; mm <<= 1) {
    s0 += __shfl_xor(s0, mm); s1 += __shfl_xor(s1, mm); s2 += __shfl_xor(s2, mm);
  }
  float dcv = dcp[0];
  int row0 = blockIdx.x * 16 + wid * 2;
  for (int r = 0; r < 2; ++r) {
    int row = row0 + r;
    const float4* xr = (const float4*)(h + (size_t)row * FIN);
    float4 xa = xr[lane], xb4 = xr[64 + lane];
    float d0, d1, d2;
    d0 = xa.x*cA0.x; d1 = xa.x*cA1.x; d2 = xa.x*cA2.x;
    d0 = fmaf(xa.y, cA0.y, d0); d1 = fmaf(xa.y, cA1.y, d1); d2 = fmaf(xa.y, cA2.y, d2);
    d0 = fmaf(xa.z, cA0.z, d0); d1 = fmaf(xa.z, cA1.z, d1); d2 = fmaf(xa.z, cA2.z, d2);
    d0 = fmaf(xa.w, cA0.w, d0); d1 = fmaf(xa.w, cA1.w, d1); d2 = fmaf(xa.w, cA2.w, d2);
    d0 = fmaf(xb4.x, cB0.x, d0); d1 = fmaf(xb4.x, cB1.x, d1); d2 = fmaf(xb4.x, cB2.x, d2);
    d0 = fmaf(xb4.y, cB0.y, d0); d1 = fmaf(xb4.y, cB1.y, d1); d2 = fmaf(xb4.y, cB2.y, d2);
    d0 = fmaf(xb4.z, cB0.z, d0); d1 = fmaf(xb4.z, cB1.z, d1); d2 = fmaf(xb4.z, cB2.z, d2);
    d0 = fmaf(xb4.w, cB0.w, d0); d1 = fmaf(xb4.w, cB1.w, d1); d2 = fmaf(xb4.w, cB2.w, d2);
    #pragma unroll
    for (int mm = 1; mm < 64; mm <<= 1) {
      d0 += __shfl_xor(d0, mm); d1 += __shfl_xor(d1, mm); d2 += __shfl_xor(d2, mm);
    }
    if (lane == 0) {
      float sr = sq[row];
      float q0 = sqrtf(fmaxf(sr + s0 - 2.f * d0, 0.f));
      float q1 = sqrtf(fmaxf(sr + s1 - 2.f * d1, 0.f));
      float q2 = sqrtf(fmaxf(sr + s2 - 2.f * d2, 0.f));
      float nr = q1;
      d1v[row * 3 + 0] = (q0 != 0.f) ? (dcv * nr / (q0 * q0)) : 0.f;
      d1v[row * 3 + 1] = (q1 != 0.f) ? (dcv * nr / (q1 * q1)) : 0.f;
      d1v[row * 3 + 2] = (q2 != 0.f) ? (dcv * nr / (q2 * q2)) : 0.f;
    }
  }
}

// ---------------- fused MFMA softmax-numerator @ Wh, K-split x4 ----------------
__global__ __launch_bounds__(256) void k_mainA(const float* __restrict__ t2,
    const __hip_bfloat16* __restrict__ WhbT, const float* __restrict__ d1v,
    const float* __restrict__ tm, float* __restrict__ Vpart, float* __restrict__ Spart) {
  int t = threadIdx.x, lane = t & 63, wid = t >> 6;
  int rb = blockIdx.x & 63, ks = blockIdx.x >> 6;
  int R0 = rb * 64, K0 = ks * 1024;
  __shared__ float t2s[3 * 1024];
  for (int idx = t; idx < 3072; idx += 256) {
    int c = idx >> 10, kl = idx & 1023;
    t2s[idx] = t2[c * NPTS + K0 + kl];
  }
  __syncthreads();
  int r = lane & 15, hi = lane >> 4;
  int row_g = R0 + wid * 16 + r;
  float a0 = d1v[row_g * 3 + 0], a1 = d1v[row_g * 3 + 1], a2 = d1v[row_g * 3 + 2];
  float M = fmaf(fabsf(a2), tm[2], fmaf(fabsf(a1), tm[1], fabsf(a0) * tm[0]));
  f32x4 acc[4];
  #pragma unroll
  for (int fn = 0; fn < 4; ++fn) acc[fn] = (f32x4){0.f, 0.f, 0.f, 0.f};
  float Sp = 0.f;
  const __hip_bfloat16* bwB[4];
  #pragma unroll
  for (int fn = 0; fn < 4; ++fn) bwB[fn] = WhbT + (size_t)(fn * 16 + r) * NPTS + K0 + hi * 8;

  for (int kst = 0; kst < 32; ++kst) {
    int kb = kst * 32 + hi * 8;
    f32x4 c0a = *(const f32x4*)&t2s[kb],           c0b = *(const f32x4*)&t2s[kb + 4];
    f32x4 c1a = *(const f32x4*)&t2s[1024 + kb],    c1b = *(const f32x4*)&t2s[1024 + kb + 4];
    f32x4 c2a = *(const f32x4*)&t2s[2048 + kb],    c2b = *(const f32x4*)&t2s[2048 + kb + 4];
    float pv[8];
    #pragma unroll
    for (int j = 0; j < 4; ++j) {
      float L  = fmaf(a0, c0a[j], fmaf(a1, c1a[j], fmaf(a2, c2a[j], -M)));
      pv[j] = __expf(L);
      float L2 = fmaf(a0, c0b[j], fmaf(a1, c1b[j], fmaf(a2, c2b[j], -M)));
      pv[4 + j] = __expf(L2);
    }
    Sp += ((pv[0] + pv[1]) + (pv[2] + pv[3])) + ((pv[4] + pv[5]) + (pv[6] + pv[7]));
    union { bf16x8 v; __hip_bfloat162 h2[4]; } pa;
    #pragma unroll
    for (int jj = 0; jj < 4; ++jj) {
      float2 f2; f2.x = pv[2 * jj]; f2.y = pv[2 * jj + 1];
      pa.h2[jj] = __float22bfloat162_rn(f2);
    }
    #pragma unroll
    for (int fn = 0; fn < 4; ++fn) {
      bf16x8 bw = *(const bf16x8*)(bwB[fn] + kst * 32);
      acc[fn] = __builtin_amdgcn_mfma_f32_16x16x32_bf16(pa.v, bw, acc[fn], 0, 0, 0);
    }
  }
  Sp += __shfl_xor(Sp, 16);
  Sp += __shfl_xor(Sp, 32);
  if (hi == 0) Spart[row_g * 4 + ks] = Sp;
  #pragma unroll
  for (int fn = 0; fn < 4; ++fn)
    #pragma unroll
    for (int q = 0; q < 4; ++q)
      Vpart[(size_t)ks * (NPTS * FOUT) + (size_t)(R0 + wid * 16 + hi * 4 + q) * FOUT + fn * 16 + r] = acc[fn][q];
}

// ---------------- combine partials: divide, ELU ----------------
__global__ __launch_bounds__(256) void k_comb(const float* __restrict__ Vpart,
    const float* __restrict__ Spart, const float* __restrict__ d1v,
    const float* __restrict__ tm, float* __restrict__ out) {
  int gid = blockIdx.x * 256 + threadIdx.x;
  int row = gid >> 6;
  float V = (Vpart[gid] + Vpart[NPTS * FOUT + gid])
          + (Vpart[2 * NPTS * FOUT + gid] + Vpart[3 * NPTS * FOUT + gid]);
  float s = (Spart[row * 4 + 0] + Spart[row * 4 + 1]) + (Spart[row * 4 + 2] + Spart[row * 4 + 3]);
  float a0 = d1v[row * 3 + 0], a1 = d1v[row * 3 + 1], a2 = d1v[row * 3 + 2];
  float M = fmaf(fabsf(a2), tm[2], fmaf(fabsf(a1), tm[1], fabsf(a0) * tm[0]));
  s += 3.f * __expf(-M);
  float o = V / s;
  out[gid] = o > 0.f ? o : expm1f(o);
}

extern "C" void kernel_launch(void* const* d_in, const int* in_sizes, int n_in,
                              void* d_out, int out_size, void* d_ws, size_t ws_size,
                              hipStream_t stream) {
  const float* h  = (const float*)d_in[0];
  const float* W  = (const float*)d_in[2];
  const float* t2 = (const float*)d_in[5];
  float* out = (float*)d_out;

  char* ws = (char*)d_ws;
  __hip_bfloat16* xb = (__hip_bfloat16*)ws;
  float* F = (float*)(ws + (size_t)NPTS * FIN * 2);
  float* sq      = F + 0;                  // 4096
  int*   m1      = (int*)(F + 4096);       // 4096
  float* dkm     = F + 8192;               // 4096
  float* d1v     = F + 16384;              // 12288
  float* Wh      = F + 32768;              // 262144
  float* centers = F + 294912;             // 1536
  float* bestv0  = F + 296448;             // 256
  int*   besti0  = (int*)(F + 296704);     // 256
  float* bestv1  = F + 296960;             // 256
  int*   besti1  = (int*)(F + 297216);     // 256
  int*   b1s     = (int*)(F + 297472);     // 4
  float* pcnts   = F + 297476;             // 768
  float* dcp     = F + 298244;             // 1
  float* tmv     = F + 298248;             // 3
  float* psums   = F + 298496;             // 393216
  float* Spart   = F + 691712;             // 16384
  float* Vpart   = F + 708096;             // 1048576
  __hip_bfloat16* WhbT = (__hip_bfloat16*)(F + 1756672); // 262144 bf16

  k_prep<<<NPTS / 4, 256, 0, stream>>>(h, W, xb, sq, m1, Wh);
  k_tr<<<16, 256, 0, stream>>>(Wh, WhbT);
  k_gram2<<<528, 256, 0, stream>>>(xb, sq, m1);
  k_dckstar<<<1, 1024, 0, stream>>>(m1, t2, Wh, dcp, tmv, out);

  k_asgn<0><<<256, 512, 0, stream>>>(h, sq, centers, dkm, nullptr, nullptr,
                                     bestv0, besti0, b1s, psums, pcnts);
  k_asgn<1><<<256, 512, 0, stream>>>(h, sq, centers, dkm, bestv0, besti0,
                                     bestv1, besti1, b1s, psums, pcnts);
  k_initc<<<1, 256, 0, stream>>>(h, bestv1, besti1, b1s, centers);
  for (int it = 0; it < 10; ++it) {
    k_asgn<2><<<256, 512, 0, stream>>>(h, sq, centers, dkm, nullptr, nullptr,
                                       bestv0, besti0, b1s, psums, pcnts);
    k_upd<<<6, 256, 0, stream>>>(psums, pcnts, centers);
  }
  k_d1val<<<256, 512, 0, stream>>>(h, sq, centers, dcp, d1v);

  k_mainA<<<256, 256, 0, stream>>>(t2, WhbT, d1v, tmv, Vpart, Spart);
  k_comb<<<1024, 256, 0, stream>>>(Vpart, Spart, d1v, tmv, out);
}